// Round 15
// baseline (446.156 us; speedup 1.0000x reference)
//
#include <hip/hip_runtime.h>
#include <hip/hip_bf16.h>
#include <math.h>

typedef __attribute__((ext_vector_type(8))) short short8v;
typedef __attribute__((ext_vector_type(4))) float float4v;

__device__ inline unsigned short f2bf(float f) {
  __hip_bfloat16 h = __float2bfloat16(f);
  return *reinterpret_cast<unsigned short*>(&h);
}
__device__ inline unsigned pk2(float a, float b) {
  return (unsigned)f2bf(a) | ((unsigned)f2bf(b) << 16);
}
__device__ inline float bfl(unsigned u) { return __uint_as_float(u << 16); }
__device__ inline float bfh(unsigned u) { return __uint_as_float(u & 0xffff0000u); }
__device__ inline float bfs(short s) { return __uint_as_float(((unsigned)(unsigned short)s) << 16); }

// O-in-sK swizzled index: row tok (96 shorts), 16B slots XOR'd within row
__device__ inline int o_idx(int tok, int ch) {
  int slot = ch >> 3;
  int sw = slot < 8 ? (slot ^ (tok & 7)) : (8 + ((slot - 8) ^ (tok & 3)));
  return tok * 96 + sw * 8 + (ch & 7);
}

// ---------------- merged prologue ----------------
__global__ __launch_bounds__(256) void k_prep(
    const int* __restrict__ sidx, int* __restrict__ T,
    const float* __restrict__ w1, short* __restrict__ Wt1,
    const float* __restrict__ w2, short* __restrict__ Wt2,
    const float* __restrict__ qkvw, short* __restrict__ Wqkv,
    const float* __restrict__ atw, short* __restrict__ Waw,
    const float* __restrict__ encw, short* __restrict__ Wenc,
    const float* __restrict__ pew, short* __restrict__ Wpe,
    const float* __restrict__ recw, short* __restrict__ Wrec,
    const float* __restrict__ rpb, float* __restrict__ Bt) {
  int bx = blockIdx.x;
  int tid = threadIdx.x;
  if (bx < 1944) {
    const float* w = bx < 972 ? w1 : w2;
    short* Wt = bx < 972 ? Wt1 : Wt2;
    int id = (bx < 972 ? bx : bx - 972) * 256 + tid;
    if (id < 248832) {
      float v = w[id];
      int o = id / 2592; int rem = id % 2592; int i = rem / 27; int tap = rem % 27;
      Wt[(tap * 96 + o) * 96 + i] = (short)f2bf(v);
    }
  } else if (bx < 2052) {
    int id = (bx - 1944) * 256 + tid;
    if (id < 27648) Wqkv[id] = (short)f2bf(qkvw[id]);
  } else if (bx < 2088) {
    int id = (bx - 2052) * 256 + tid;
    if (id < 9216) Waw[id] = (short)f2bf(atw[id]);
  } else if (bx < 2124) {
    int id = (bx - 2088) * 256 + tid;
    if (id < 9216) Wenc[id] = (short)f2bf(encw[id]);
  } else if (bx < 2148) {
    int id = (bx - 2124) * 256 + tid;
    if (id < 6144) Wpe[id] = (short)f2bf(pew[id]);
  } else if (bx < 2196) {
    int id = (bx - 2148) * 256 + tid;
    if (id < 12288) {
      int i = id >> 7, j = id & 127;
      Wrec[j * 96 + i] = (short)f2bf(recw[id]);
    }
  } else if (bx < 2244) {
    int id = (bx - 2196) * 256 + tid;
    if (id < 12288) {
      int head = id >> 12, rem = id & 4095, n = rem >> 6, m = rem & 63;
      int dz = (n >> 4) - (m >> 4), dh = ((n >> 2) & 3) - ((m >> 2) & 3), dw = (n & 3) - (m & 3);
      Bt[id] = rpb[((dz + 3) * 49 + (dh + 3) * 7 + (dw + 3)) * 3 + head];
    }
  } else {
    __shared__ float pos[12];
    int t = tid;
    if (t < 12) pos[t] = (float)sidx[t];
    __syncthreads();
    if (t < 64) {
      float zq = (float)t;
      int r = 0;
      while (r < 12 && pos[r] < zq) r++;
      int lft = r - 1; if (lft < 0) lft = 0; if (lft > 11) lft = 11;
      int rc = r; if (rc > 11) rc = 11;
      float lp = pos[lft], rp = pos[rc], d = rp - lp;
      float w = d > 0.f ? (zq - lp) / d : 0.5f;
      T[t] = lft; T[64 + t] = rc; ((float*)T)[128 + t] = w;
    } else if (t < 128) {
      int zq = t - 64;
      float zqf = (float)zq;
      if (zq < 32) {
        int r = 0;
        while (r < 12 && pos[r] * 0.5f < zqf) r++;
        int lft = r - 1; if (lft < 0) lft = 0; if (lft > 11) lft = 11;
        int rc = r; if (rc > 11) rc = 11;
        float lp = pos[lft] * 0.5f, rp = pos[rc] * 0.5f, d = rp - lp;
        float w = d > 0.f ? (zqf - lp) / d : 0.5f;
        T[192 + zq] = lft; T[224 + zq] = rc; ((float*)T)[256 + zq] = w;
      }
    }
  }
}

// ---------------- patch embed (MFMA) + LayerNorm ----------------
__global__ __launch_bounds__(256) void k_pe(const float* __restrict__ sp, const short* __restrict__ Wpe,
    const float* __restrict__ pb, const float* __restrict__ pg, const float* __restrict__ pbeta,
    float* __restrict__ f1) {
  int x = blockIdx.x;
  int b = x / 384, z = (x / 32) % 12, h = x % 32;
  __shared__ short sB[32][72];
  __shared__ float sF[32][97];
  __shared__ float sM[32], sR[32];
  int tid = threadIdx.x;
  for (int id = tid; id < 2048; id += 256) {
    int c = id >> 9, p = (id >> 7) & 3, col = id & 127;
    float v = sp[(((b * 4 + c) * 12 + z) * 128 + h * 4 + p) * 128 + col];
    sB[col >> 2][c * 16 + p * 4 + (col & 3)] = (short)f2bf(v);
  }
  __syncthreads();
  int w = tid >> 6, l = tid & 63, lo = l & 15, ig = l >> 4;
  int nt = w & 1, mbase = (w >> 1) * 3;
  short8v bfrag[2];
  #pragma unroll
  for (int kc = 0; kc < 2; kc++)
    bfrag[kc] = *(const short8v*)&sB[nt * 16 + lo][kc * 32 + ig * 8];
  #pragma unroll
  for (int mi = 0; mi < 3; mi++) {
    int m = mbase + mi;
    float4v acc = (float4v){0.f, 0.f, 0.f, 0.f};
    #pragma unroll
    for (int kc = 0; kc < 2; kc++) {
      short8v a = *(const short8v*)(Wpe + (size_t)(m * 16 + lo) * 64 + kc * 32 + ig * 8);
      acc = __builtin_amdgcn_mfma_f32_16x16x32_bf16(a, bfrag[kc], acc, 0, 0, 0);
    }
    int wcoord = nt * 16 + lo;
    #pragma unroll
    for (int r = 0; r < 4; r++) {
      int d = m * 16 + ig * 4 + r;
      sF[wcoord][d] = acc[r] + pb[d];
    }
  }
  __syncthreads();
  if (tid < 32) {
    int wv = tid;
    float s = 0.f, ss = 0.f;
    for (int d = 0; d < 96; d++) { float v = sF[wv][d]; s += v; ss += v * v; }
    float m = s * (1.f / 96.f);
    float var = ss * (1.f / 96.f) - m * m;
    sM[wv] = m; sR[wv] = rsqrtf(var + 1e-5f);
  }
  __syncthreads();
  for (int id = tid; id < 3072; id += 256) {
    int d = id >> 5, wv = id & 31;
    float v = (sF[wv][d] - sM[wv]) * sR[wv] * pg[d] + pbeta[d];
    f1[(((b * 96 + d) * 12 + z) * 32 + h) * 32 + wv] = v;
  }
}

// ---------------- z-interp + encoder proj (MFMA) -> X token-major bf16 ----------------
__global__ __launch_bounds__(256) void k_ie(const float* __restrict__ f1, const float* __restrict__ ef,
    const short* __restrict__ Wenc, const float* __restrict__ eb, const int* __restrict__ T,
    unsigned* __restrict__ Xg) {
  int x = blockIdx.x;
  int b = x >> 9, chunk = x & 511;
  int v0 = chunk * 64;
  int z = v0 >> 10, rp = v0 & 1023;
  int zl = T[192 + z], zr = T[224 + z];
  float wt = ((const float*)T)[256 + z];
  __shared__ short sEb[64][104];
  int tid = threadIdx.x;
  for (int id = tid; id < 6144; id += 256) {
    int c = id >> 6, vs = id & 63;
    sEb[vs][c] = (short)f2bf(ef[(size_t)(b * 96 + c) * 32768 + v0 + vs]);
  }
  __syncthreads();
  int w = tid >> 6, l = tid & 63, lo = l & 15, ig = l >> 4;
  int vcol = w * 16 + lo;
  short8v bfrag[3];
  #pragma unroll
  for (int kc = 0; kc < 3; kc++)
    bfrag[kc] = *(const short8v*)&sEb[vcol][kc * 32 + ig * 8];
  float4v acc[6];
  #pragma unroll
  for (int m = 0; m < 6; m++) {
    acc[m] = (float4v){0.f, 0.f, 0.f, 0.f};
    #pragma unroll
    for (int kc = 0; kc < 3; kc++) {
      short8v a = *(const short8v*)(Wenc + (size_t)(m * 16 + lo) * 96 + kc * 32 + ig * 8);
      acc[m] = __builtin_amdgcn_mfma_f32_16x16x32_bf16(a, bfrag[kc], acc[m], 0, 0, 0);
    }
  }
  int zb = z >> 2, tz = z & 3;
  int h0 = (chunk & 15) * 2;
  int h = h0 + (vcol >> 5), wc = vcol & 31;
  int win = ((b * 8 + zb) * 8 + (h >> 2)) * 8 + (wc >> 2);
  int t = tz * 16 + (h & 3) * 4 + (wc & 3);
  size_t xbase = (size_t)(win * 64 + t) * 48;
  float wl = 1.f - wt;
  #pragma unroll
  for (int m = 0; m < 6; m++) {
    #pragma unroll
    for (int rr = 0; rr < 2; rr++) {
      int d0 = m * 16 + ig * 4 + rr * 2;
      const float* p1a = f1 + ((size_t)(b * 96 + d0) * 12 + zl) * 1024 + rp + vcol;
      const float* p2a = f1 + ((size_t)(b * 96 + d0) * 12 + zr) * 1024 + rp + vcol;
      const float* p1b = f1 + ((size_t)(b * 96 + d0 + 1) * 12 + zl) * 1024 + rp + vcol;
      const float* p2b = f1 + ((size_t)(b * 96 + d0 + 1) * 12 + zr) * 1024 + rp + vcol;
      float va = acc[m][rr * 2] + eb[d0] + wl * p1a[0] + wt * p2a[0];
      float vb = acc[m][rr * 2 + 1] + eb[d0 + 1] + wl * p1b[0] + wt * p2b[0];
      Xg[xbase + m * 8 + ig * 2 + rr] = pk2(va, vb);
    }
  }
}

// ---------------- fused LN + QKV + attention + proj ----------------
__global__ __launch_bounds__(256) void k_fatt(const unsigned* __restrict__ Xg,
    const short* __restrict__ Wq, const float* __restrict__ qb,
    const float* __restrict__ lg, const float* __restrict__ lb,
    const short* __restrict__ Wa, const float* __restrict__ ab,
    const float* __restrict__ Bt, short* __restrict__ Xt) {
  int win = blockIdx.x;
  __shared__ short sA[64][104];
  __shared__ short sQP[4][16][104];
  __shared__ short sK[6144];
  __shared__ short sVt[96][72];
  __shared__ float sMn[64], sRs[64];
  int tid = threadIdx.x;
  int w = tid >> 6, l = tid & 63, lo = l & 15, ig = l >> 4;
  const float scale = 0.17677669529663687f;

  for (int id = tid; id < 3072; id += 256) {
    int row = id / 48, c2 = id % 48;
    *(unsigned*)&sA[row][c2 * 2] = Xg[(size_t)(win * 64 + row) * 48 + c2];
  }
  __syncthreads();
  {
    int token = tid >> 2, jl = tid & 3;
    float s = 0.f, ss = 0.f;
    #pragma unroll
    for (int i = 0; i < 12; i++) {
      unsigned u = *(unsigned*)&sA[token][jl * 24 + i * 2];
      float v0 = bfl(u), v1 = bfh(u);
      s += v0 + v1; ss += v0 * v0 + v1 * v1;
    }
    s += __shfl_xor(s, 1); ss += __shfl_xor(ss, 1);
    s += __shfl_xor(s, 2); ss += __shfl_xor(ss, 2);
    if (jl == 0) {
      float m = s * (1.f / 96.f);
      sMn[token] = m;
      sRs[token] = rsqrtf(ss * (1.f / 96.f) - m * m + 1e-5f);
    }
  }
  __syncthreads();
  {
    int tok = w * 16 + lo;
    float m = sMn[tok], rr = sRs[tok];
    short8v a[3];
    #pragma unroll
    for (int kc = 0; kc < 3; kc++) {
      short8v raw = *(const short8v*)&sA[tok][kc * 32 + ig * 8];
      short8v t;
      #pragma unroll
      for (int jj = 0; jj < 8; jj++) {
        int c = kc * 32 + ig * 8 + jj;
        float v = (bfs(raw[jj]) - m) * rr * lg[c] + lb[c];
        t[jj] = (short)f2bf(v);
      }
      a[kc] = t;
    }
    for (int nt = 0; nt < 18; nt++) {
      float4v acc = (float4v){0.f, 0.f, 0.f, 0.f};
      #pragma unroll
      for (int kc = 0; kc < 3; kc++) {
        short8v bfr = *(const short8v*)(Wq + (size_t)(nt * 16 + lo) * 96 + kc * 32 + ig * 8);
        acc = __builtin_amdgcn_mfma_f32_16x16x32_bf16(a[kc], bfr, acc, 0, 0, 0);
      }
      int out = nt * 16 + lo;
      float bias = qb[out];
      if (nt < 6) {
        int head = out >> 5, c = out & 31;
        #pragma unroll
        for (int r = 0; r < 4; r++)
          sQP[w][ig * 4 + r][head * 32 + c] = (short)f2bf((acc[r] + bias) * scale);
      } else if (nt < 12) {
        int o2 = out - 96, head = o2 >> 5, c = o2 & 31;
        #pragma unroll
        for (int r = 0; r < 4; r++) {
          int row = head * 64 + w * 16 + ig * 4 + r;
          sK[row * 32 + (((c >> 3) ^ ((row >> 1) & 3)) << 3) + (c & 7)] =
              (short)f2bf(acc[r] + bias);
        }
      } else {
        int o2 = out - 192;
        #pragma unroll
        for (int r = 0; r < 4; r++)
          sVt[o2][w * 16 + ig * 4 + r] = (short)f2bf(acc[r] + bias);
      }
    }
  }
  __syncthreads();
  short8v qf[3];
  #pragma unroll
  for (int h = 0; h < 3; h++)
    qf[h] = *(const short8v*)&sQP[w][lo][h * 32 + ig * 8];
  float oreg[3][2][4];
  #pragma unroll
  for (int h = 0; h < 3; h++) {
    short8v kf[4];
    #pragma unroll
    for (int nt = 0; nt < 4; nt++) {
      int row = h * 64 + nt * 16 + lo;
      kf[nt] = *(const short8v*)&sK[row * 32 + ((ig ^ ((row >> 1) & 3)) << 3)];
    }
    float4v s[4];
    #pragma unroll
    for (int nt = 0; nt < 4; nt++)
      s[nt] = __builtin_amdgcn_mfma_f32_16x16x32_bf16(qf[h], kf[nt], (float4v){0.f, 0.f, 0.f, 0.f}, 0, 0, 0);
    const float* bt = Bt + h * 4096;
    #pragma unroll
    for (int r = 0; r < 4; r++) {
      int tok = w * 16 + ig * 4 + r;
      float v[4];
      float mx = -1e30f;
      #pragma unroll
      for (int nt = 0; nt < 4; nt++) {
        v[nt] = s[nt][r] + bt[tok * 64 + nt * 16 + lo];
        mx = fmaxf(mx, v[nt]);
      }
      mx = fmaxf(mx, __shfl_xor(mx, 1));
      mx = fmaxf(mx, __shfl_xor(mx, 2));
      mx = fmaxf(mx, __shfl_xor(mx, 4));
      mx = fmaxf(mx, __shfl_xor(mx, 8));
      float sm = 0.f;
      #pragma unroll
      for (int nt = 0; nt < 4; nt++) { v[nt] = __expf(v[nt] - mx); sm += v[nt]; }
      sm += __shfl_xor(sm, 1);
      sm += __shfl_xor(sm, 2);
      sm += __shfl_xor(sm, 4);
      sm += __shfl_xor(sm, 8);
      float inv = 1.f / sm;
      #pragma unroll
      for (int nt = 0; nt < 4; nt++)
        sQP[w][ig * 4 + r][nt * 16 + lo] = (short)f2bf(v[nt] * inv);
    }
    short8v pa[2];
    #pragma unroll
    for (int kc = 0; kc < 2; kc++)
      pa[kc] = *(const short8v*)&sQP[w][lo][kc * 32 + ig * 8];
    #pragma unroll
    for (int ct = 0; ct < 2; ct++) {
      short8v vb0 = *(const short8v*)&sVt[h * 32 + ct * 16 + lo][ig * 8];
      short8v vb1 = *(const short8v*)&sVt[h * 32 + ct * 16 + lo][32 + ig * 8];
      float4v o = __builtin_amdgcn_mfma_f32_16x16x32_bf16(pa[0], vb0, (float4v){0.f, 0.f, 0.f, 0.f}, 0, 0, 0);
      o = __builtin_amdgcn_mfma_f32_16x16x32_bf16(pa[1], vb1, o, 0, 0, 0);
      #pragma unroll
      for (int r = 0; r < 4; r++)
        oreg[h][ct][r] = o[r];
    }
  }
  __syncthreads();
  #pragma unroll
  for (int h = 0; h < 3; h++)
    #pragma unroll
    for (int ct = 0; ct < 2; ct++)
      #pragma unroll
      for (int r = 0; r < 4; r++) {
        int tok = w * 16 + ig * 4 + r;
        int ch = h * 32 + ct * 16 + lo;
        sK[o_idx(tok, ch)] = (short)f2bf(oreg[h][ct][r]);
      }
  {
    int tok2 = w * 16 + lo;
    short8v a[3];
    #pragma unroll
    for (int kc = 0; kc < 3; kc++) {
      int slot = kc * 4 + ig;
      int sw = slot < 8 ? (slot ^ (tok2 & 7)) : (8 + ((slot - 8) ^ (tok2 & 3)));
      a[kc] = *(const short8v*)&sK[tok2 * 96 + sw * 8];
    }
    #pragma unroll
    for (int nt = 0; nt < 6; nt++) {
      float4v acc = (float4v){0.f, 0.f, 0.f, 0.f};
      #pragma unroll
      for (int kc = 0; kc < 3; kc++) {
        short8v bfr = *(const short8v*)(Wa + (size_t)(nt * 16 + lo) * 96 + kc * 32 + ig * 8);
        acc = __builtin_amdgcn_mfma_f32_16x16x32_bf16(a[kc], bfr, acc, 0, 0, 0);
      }
      int out = nt * 16 + lo;
      float bias = ab[out];
      #pragma unroll
      for (int r = 0; r < 4; r++) {
        int tok = w * 16 + ig * 4 + r;
        float res = bfs(sA[tok][out]);
        sA[tok][out] = (short)f2bf(acc[r] + bias + res);
      }
    }
  }
  __syncthreads();
  int b = win >> 9, zb = (win >> 6) & 7, hb = (win >> 3) & 7, wb = win & 7;
  for (int id = tid; id < 3072; id += 256) {
    int cc = id >> 10, rem = id & 1023, t = rem >> 4, ilp = rem & 15;
    unsigned pk = *(unsigned*)&sA[t][cc * 32 + ilp * 2];
    int tz = t >> 4, th = (t >> 2) & 3, tw = t & 3;
    size_t vox = (size_t)(zb * 4 + tz) * 1024 + (hb * 4 + th) * 32 + wb * 4 + tw;
    ((unsigned*)Xt)[((size_t)(b * 3 + cc) * 32768 + vox) * 16 + ilp] = pk;
  }
}

// ---------------- MFMA conv 3x3x3: 2z x 4h x 32w x 96o, async-STAGE prefetch, bf16 y ----------------
__global__ __launch_bounds__(256) void k_convM(const short* __restrict__ Xt,
    const short* __restrict__ Wt, const float* __restrict__ cb, short* __restrict__ y16,
    float* __restrict__ stats) {
  int x = blockIdx.x;
  int b = x >> 7, zp = (x >> 3) & 15, hq = x & 7;
  int tid = threadIdx.x;
  int wvi = tid >> 6, l = tid & 63;
  int lo = l & 15, ig = l >> 4;
  int hp = wvi & 1, mh = wvi >> 1;
  __shared__ short Xl[816 * 32];
  __shared__ float sG[16];
  if (tid < 16) sG[tid] = 0.f;
  float4v acc[3][2][2][2];
  #pragma unroll
  for (int mi = 0; mi < 3; mi++)
    #pragma unroll
    for (int zo = 0; zo < 2; zo++)
      #pragma unroll
      for (int hr = 0; hr < 2; hr++)
        #pragma unroll
        for (int n = 0; n < 2; n++) acc[mi][zo][hr][n] = (float4v){0.f, 0.f, 0.f, 0.f};

  // precompute per-thread staging map (c-independent)
  int voff[13];     // element offset within channel plane, -1 = zero-fill, -2 = no slot
  int laddr[13];
  #pragma unroll
  for (int r = 0; r < 13; r++) {
    int id = tid + 256 * r;
    if (id < 3264) {
      int seg = id & 3, q = id >> 2;
      int zz = q / 204, rem = q - zz * 204;
      int hh = rem / 34, ww = rem - hh * 34;
      int gz = zp * 2 + zz - 1, gh = hq * 4 + hh - 1, gw = ww - 1;
      bool ok = gz >= 0 && gz < 32 && gh >= 0 && gh < 32 && gw >= 0 && gw < 32;
      voff[r] = ok ? (((gz << 10) + (gh << 5) + gw) * 32 + seg * 8) : -1;
      int slot = seg ^ ((q >> 1) & 3);
      laddr[r] = q * 32 + slot * 8;
    } else { voff[r] = -2; laddr[r] = 0; }
  }
  const size_t cbase = (size_t)(b * 3) * 1048576;
  int4 rg[13];
  #pragma unroll
  for (int r = 0; r < 13; r++) {
    int4 v = {0, 0, 0, 0};
    if (voff[r] >= 0) v = *(const int4*)(Xt + cbase + voff[r]);
    rg[r] = v;
  }

  for (int c = 0; c < 3; c++) {
    #pragma unroll
    for (int r = 0; r < 13; r++)
      if (voff[r] != -2) *(int4*)(&Xl[laddr[r]]) = rg[r];
    __syncthreads();
    if (c < 2) {
      #pragma unroll
      for (int r = 0; r < 13; r++) {
        int4 v = {0, 0, 0, 0};
        if (voff[r] >= 0) v = *(const int4*)(Xt + cbase + (size_t)(c + 1) * 1048576 + voff[r]);
        rg[r] = v;
      }
    }
    for (int dh = 0; dh < 3; dh++) {
      for (int dwv = 0; dwv < 3; dwv++) {
        short8v bfr[4][2][2];
        #pragma unroll
        for (int zr = 0; zr < 4; zr++)
          #pragma unroll
          for (int hr = 0; hr < 2; hr++)
            #pragma unroll
            for (int n = 0; n < 2; n++) {
              int vox = (zr * 6 + hp * 2 + hr + dh) * 34 + n * 16 + lo + dwv;
              bfr[zr][hr][n] = *(const short8v*)&Xl[vox * 32 + ((ig ^ ((vox >> 1) & 3)) * 8)];
            }
        #pragma unroll
        for (int dz = 0; dz < 3; dz++) {
          int tap = dz * 9 + dh * 3 + dwv;
          #pragma unroll
          for (int mi = 0; mi < 3; mi++) {
            short8v wf = *(const short8v*)(Wt +
                ((size_t)(tap * 96 + (mh * 3 + mi) * 16 + lo)) * 96 + c * 32 + ig * 8);
            #pragma unroll
            for (int zo = 0; zo < 2; zo++)
              #pragma unroll
              for (int hr = 0; hr < 2; hr++)
                #pragma unroll
                for (int n = 0; n < 2; n++)
                  acc[mi][zo][hr][n] = __builtin_amdgcn_mfma_f32_16x16x32_bf16(wf, bfr[zo + dz][hr][n], acc[mi][zo][hr][n], 0, 0, 0);
          }
        }
      }
    }
    if (c < 2) __syncthreads();
  }
  #pragma unroll
  for (int mi = 0; mi < 3; mi++) {
    #pragma unroll
    for (int r = 0; r < 4; r++) {
      int o = (mh * 3 + mi) * 16 + ig * 4 + r;
      float cbo = cb[o];
      float s = 0.f, ss = 0.f;
      #pragma unroll
      for (int zo = 0; zo < 2; zo++)
        #pragma unroll
        for (int hr = 0; hr < 2; hr++)
          #pragma unroll
          for (int n = 0; n < 2; n++) {
            float v = acc[mi][zo][hr][n][r] + cbo;
            int z = zp * 2 + zo;
            int h = hq * 4 + hp * 2 + hr;
            int vcol = n * 16 + lo;
            y16[((size_t)(b * 96 + o) << 15) + (z << 10) + (h << 5) + vcol] = (short)f2bf(v);
            s += v; ss += v * v;
          }
      s += __shfl_xor(s, 1); ss += __shfl_xor(ss, 1);
      s += __shfl_xor(s, 2); ss += __shfl_xor(ss, 2);
      s += __shfl_xor(s, 4); ss += __shfl_xor(ss, 4);
      s += __shfl_xor(s, 8); ss += __shfl_xor(ss, 8);
      if (lo == 0) {
        int gl = o / 12;
        atomicAdd(&sG[gl * 2], s);
        atomicAdd(&sG[gl * 2 + 1], ss);
      }
    }
  }
  __syncthreads();
  if (tid < 16) atomicAdd(&stats[b * 16 + tid], sG[tid]);
}

// ---------------- GN apply + GELU (bf16 y in) -> bf16 conv layout ----------------
__global__ __launch_bounds__(256) void k_gn(const short* __restrict__ y16, const float* __restrict__ stats,
    const float* __restrict__ gg, const float* __restrict__ gb, short* __restrict__ xt) {
  int x = blockIdx.x;
  int b = x / 1536, r = x % 1536, c = r / 512, vt = r % 512;
  int v0 = vt * 64;
  __shared__ float sT[64][33];
  int tid = threadIdx.x;
  const float invN = 1.f / 393216.f;
  {
    int ol = tid >> 3, vq = tid & 7;
    int o = c * 32 + ol, g = b * 8 + o / 12;
    float m = stats[2 * g] * invN;
    float var = stats[2 * g + 1] * invN - m * m;
    float rs = rsqrtf(var + 1e-5f) * gg[o];
    float bb = gb[o];
    short8v yv = *(const short8v*)&y16[((size_t)(b * 96 + o) << 15) + v0 + vq * 8];
    #pragma unroll
    for (int j = 0; j < 8; j++) {
      float val = (bfs(yv[j]) - m) * rs + bb;
      sT[vq * 8 + j][ol] = 0.5f * val * (1.f + erff(val * 0.70710678118654752f));
    }
  }
  __syncthreads();
  for (int id = tid; id < 1024; id += 256) {
    int v = id >> 4, p = id & 15;
    ((unsigned*)xt)[((size_t)(b * 3 + c) * 32768 + v0 + v) * 16 + p] = pk2(sT[v][2 * p], sT[v][2 * p + 1]);
  }
}

// ---------------- reconstruct (MFMA) + baseline z-interp ----------------
__global__ __launch_bounds__(256) void k_final(const short* __restrict__ f5b, const float* __restrict__ sp,
    const short* __restrict__ Wrec, const float* __restrict__ rb, const int* __restrict__ T,
    float* __restrict__ out) {
  int x = blockIdx.x;
  int b = x >> 10, chunk = x & 1023;
  int z = chunk >> 5, h = chunk & 31;
  int v0 = chunk * 32;
  int tid = threadIdx.x;
  int w = tid >> 6, l = tid & 63, lo = l & 15, ig = l >> 4;
  short8v afrag[2][3];
  #pragma unroll
  for (int mt = 0; mt < 2; mt++)
    #pragma unroll
    for (int kc = 0; kc < 3; kc++)
      afrag[mt][kc] = *(const short8v*)(f5b +
          ((size_t)(b * 3 + kc) * 32768 + v0 + mt * 16 + lo) * 32 + ig * 8);
  float4v acc[2][2];
  #pragma unroll
  for (int nt2 = 0; nt2 < 2; nt2++) {
    int jt = w * 2 + nt2;
    #pragma unroll
    for (int mt = 0; mt < 2; mt++) acc[mt][nt2] = (float4v){0.f, 0.f, 0.f, 0.f};
    #pragma unroll
    for (int kc = 0; kc < 3; kc++) {
      short8v bfr = *(const short8v*)(Wrec + (size_t)(jt * 16 + lo) * 96 + kc * 32 + ig * 8);
      #pragma unroll
      for (int mt = 0; mt < 2; mt++)
        acc[mt][nt2] = __builtin_amdgcn_mfma_f32_16x16x32_bf16(afrag[mt][kc], bfr, acc[mt][nt2], 0, 0, 0);
    }
  }
  const float* w64 = (const float*)(T + 128);
  #pragma unroll
  for (int mt = 0; mt < 2; mt++)
    #pragma unroll
    for (int nt2 = 0; nt2 < 2; nt2++) {
      int jt = w * 2 + nt2;
      #pragma unroll
      for (int r = 0; r < 4; r++) {
        int wv = mt * 16 + ig * 4 + r;
        int j = jt * 16 + lo;
        int o = j >> 5, dd = (j >> 4) & 1, e = (j >> 2) & 3, ff = j & 3;
        int Z = 2 * z + dd, H = 4 * h + e, W = 4 * wv + ff;
        int zl = T[Z], zr = T[64 + Z];
        float bw = w64[Z];
        const float* spb = sp + (size_t)(b * 4 + o) * 196608;
        float bval = (1.f - bw) * spb[(size_t)zl * 16384 + H * 128 + W]
                   + bw * spb[(size_t)zr * 16384 + H * 128 + W];
        out[((size_t)(b * 4 + o) * 64 + Z) * 16384 + H * 128 + W] = bval + acc[mt][nt2][r] + rb[o];
      }
    }
}

extern "C" void kernel_launch(void* const* d_in, const int* in_sizes, int n_in,
                              void* d_out, int out_size, void* d_ws, size_t ws_size,
                              hipStream_t stream) {
  const float* sp    = (const float*)d_in[0];
  const float* ef    = (const float*)d_in[1];
  const float* pe_w  = (const float*)d_in[2];
  const float* pe_b  = (const float*)d_in[3];
  const float* pe_g  = (const float*)d_in[4];
  const float* pe_be = (const float*)d_in[5];
  const float* enc_w = (const float*)d_in[6];
  const float* enc_b = (const float*)d_in[7];
  const float* ln_g  = (const float*)d_in[8];
  const float* ln_b  = (const float*)d_in[9];
  const float* qkv_w = (const float*)d_in[10];
  const float* qkv_b = (const float*)d_in[11];
  const float* at_w  = (const float*)d_in[12];
  const float* at_b  = (const float*)d_in[13];
  const float* rpb   = (const float*)d_in[14];
  const float* w1    = (const float*)d_in[15];
  const float* b1    = (const float*)d_in[16];
  const float* g1g   = (const float*)d_in[17];
  const float* g1b   = (const float*)d_in[18];
  const float* w2    = (const float*)d_in[19];
  const float* b2    = (const float*)d_in[20];
  const float* g2g   = (const float*)d_in[21];
  const float* g2b   = (const float*)d_in[22];
  const float* recw  = (const float*)d_in[23];
  const float* recb  = (const float*)d_in[24];
  const int*   sidx  = (const int*)d_in[25];
  float* out = (float*)d_out;

  char* ws = (char*)d_ws;
  unsigned* Xg = (unsigned*)ws;
  float* f1    = (float*)(ws + 25165824);
  short* XtA   = (short*)(ws + 25165824);
  short* Y16   = (short*)(ws + 50331648);
  int*   T     = (int*)(ws + 100663296);
  float* stats = (float*)(ws + 100665344);
  short* Wrec  = (short*)(ws + 100666368);

  char* dob = (char*)d_out;
  short* Wenc = (short*)(dob + 25165824);
  short* Wpe  = (short*)(dob + 25184256);
  short* Wqkv = (short*)(dob + 65937408);
  short* Waw  = (short*)(dob + 65992704);
  float* Bt   = (float*)(dob + 66011136);
  short* Wt1  = (short*)(dob + 66060288);
  short* Wt2  = (short*)(dob + 66557952);

  k_prep<<<2245, 256, 0, stream>>>(sidx, T, w1, Wt1, w2, Wt2, qkv_w, Wqkv,
                                   at_w, Waw, enc_w, Wenc, pe_w, Wpe, recw, Wrec, rpb, Bt);

  k_pe<<<1536, 256, 0, stream>>>(sp, Wpe, pe_b, pe_g, pe_be, f1);
  k_ie<<<2048, 256, 0, stream>>>(f1, ef, Wenc, enc_b, T, Xg);
  k_fatt<<<2048, 256, 0, stream>>>(Xg, Wqkv, qkv_b, ln_g, ln_b, Waw, at_b, Bt, XtA);

  hipMemsetAsync(stats, 0, 64 * sizeof(float), stream);
  k_convM<<<512, 256, 0, stream>>>(XtA, Wt1, b1, Y16, stats);
  k_gn<<<6144, 256, 0, stream>>>(Y16, stats, g1g, g1b, XtA);

  hipMemsetAsync(stats, 0, 64 * sizeof(float), stream);
  k_convM<<<512, 256, 0, stream>>>(XtA, Wt2, b2, Y16, stats);
  k_gn<<<6144, 256, 0, stream>>>(Y16, stats, g2g, g2b, XtA);

  k_final<<<4096, 256, 0, stream>>>(XtA, sp, Wrec, recb, T, out);
}

// Round 16
// 310.039 us; speedup vs baseline: 1.4390x; 1.4390x over previous
//
#include <hip/hip_runtime.h>
#include <hip/hip_bf16.h>
#include <math.h>

typedef __attribute__((ext_vector_type(8))) short short8v;
typedef __attribute__((ext_vector_type(4))) float float4v;

__device__ inline unsigned short f2bf(float f) {
  __hip_bfloat16 h = __float2bfloat16(f);
  return *reinterpret_cast<unsigned short*>(&h);
}
__device__ inline unsigned pk2(float a, float b) {
  return (unsigned)f2bf(a) | ((unsigned)f2bf(b) << 16);
}
__device__ inline float bfl(unsigned u) { return __uint_as_float(u << 16); }
__device__ inline float bfh(unsigned u) { return __uint_as_float(u & 0xffff0000u); }
__device__ inline float bfs(short s) { return __uint_as_float(((unsigned)(unsigned short)s) << 16); }

// O-in-sK swizzled index: row tok (96 shorts), 16B slots XOR'd within row
__device__ inline int o_idx(int tok, int ch) {
  int slot = ch >> 3;
  int sw = slot < 8 ? (slot ^ (tok & 7)) : (8 + ((slot - 8) ^ (tok & 3)));
  return tok * 96 + sw * 8 + (ch & 7);
}

// ---------------- merged prologue ----------------
__global__ __launch_bounds__(256) void k_prep(
    const int* __restrict__ sidx, int* __restrict__ T,
    const float* __restrict__ w1, short* __restrict__ Wt1,
    const float* __restrict__ w2, short* __restrict__ Wt2,
    const float* __restrict__ qkvw, short* __restrict__ Wqkv,
    const float* __restrict__ atw, short* __restrict__ Waw,
    const float* __restrict__ encw, short* __restrict__ Wenc,
    const float* __restrict__ pew, short* __restrict__ Wpe,
    const float* __restrict__ recw, short* __restrict__ Wrec,
    const float* __restrict__ rpb, float* __restrict__ Bt) {
  int bx = blockIdx.x;
  int tid = threadIdx.x;
  if (bx < 1944) {
    const float* w = bx < 972 ? w1 : w2;
    short* Wt = bx < 972 ? Wt1 : Wt2;
    int id = (bx < 972 ? bx : bx - 972) * 256 + tid;
    if (id < 248832) {
      float v = w[id];
      int o = id / 2592; int rem = id % 2592; int i = rem / 27; int tap = rem % 27;
      Wt[(tap * 96 + o) * 96 + i] = (short)f2bf(v);
    }
  } else if (bx < 2052) {
    int id = (bx - 1944) * 256 + tid;
    if (id < 27648) Wqkv[id] = (short)f2bf(qkvw[id]);
  } else if (bx < 2088) {
    int id = (bx - 2052) * 256 + tid;
    if (id < 9216) Waw[id] = (short)f2bf(atw[id]);
  } else if (bx < 2124) {
    int id = (bx - 2088) * 256 + tid;
    if (id < 9216) Wenc[id] = (short)f2bf(encw[id]);
  } else if (bx < 2148) {
    int id = (bx - 2124) * 256 + tid;
    if (id < 6144) Wpe[id] = (short)f2bf(pew[id]);
  } else if (bx < 2196) {
    int id = (bx - 2148) * 256 + tid;
    if (id < 12288) {
      int i = id >> 7, j = id & 127;
      Wrec[j * 96 + i] = (short)f2bf(recw[id]);
    }
  } else if (bx < 2244) {
    int id = (bx - 2196) * 256 + tid;
    if (id < 12288) {
      int head = id >> 12, rem = id & 4095, n = rem >> 6, m = rem & 63;
      int dz = (n >> 4) - (m >> 4), dh = ((n >> 2) & 3) - ((m >> 2) & 3), dw = (n & 3) - (m & 3);
      Bt[id] = rpb[((dz + 3) * 49 + (dh + 3) * 7 + (dw + 3)) * 3 + head];
    }
  } else {
    __shared__ float pos[12];
    int t = tid;
    if (t < 12) pos[t] = (float)sidx[t];
    __syncthreads();
    if (t < 64) {
      float zq = (float)t;
      int r = 0;
      while (r < 12 && pos[r] < zq) r++;
      int lft = r - 1; if (lft < 0) lft = 0; if (lft > 11) lft = 11;
      int rc = r; if (rc > 11) rc = 11;
      float lp = pos[lft], rp = pos[rc], d = rp - lp;
      float w = d > 0.f ? (zq - lp) / d : 0.5f;
      T[t] = lft; T[64 + t] = rc; ((float*)T)[128 + t] = w;
    } else if (t < 128) {
      int zq = t - 64;
      float zqf = (float)zq;
      if (zq < 32) {
        int r = 0;
        while (r < 12 && pos[r] * 0.5f < zqf) r++;
        int lft = r - 1; if (lft < 0) lft = 0; if (lft > 11) lft = 11;
        int rc = r; if (rc > 11) rc = 11;
        float lp = pos[lft] * 0.5f, rp = pos[rc] * 0.5f, d = rp - lp;
        float w = d > 0.f ? (zqf - lp) / d : 0.5f;
        T[192 + zq] = lft; T[224 + zq] = rc; ((float*)T)[256 + zq] = w;
      }
    }
  }
}

// ---------------- patch embed (MFMA) + LayerNorm ----------------
__global__ __launch_bounds__(256) void k_pe(const float* __restrict__ sp, const short* __restrict__ Wpe,
    const float* __restrict__ pb, const float* __restrict__ pg, const float* __restrict__ pbeta,
    float* __restrict__ f1) {
  int x = blockIdx.x;
  int b = x / 384, z = (x / 32) % 12, h = x % 32;
  __shared__ short sB[32][72];
  __shared__ float sF[32][97];
  __shared__ float sM[32], sR[32];
  int tid = threadIdx.x;
  for (int id = tid; id < 2048; id += 256) {
    int c = id >> 9, p = (id >> 7) & 3, col = id & 127;
    float v = sp[(((b * 4 + c) * 12 + z) * 128 + h * 4 + p) * 128 + col];
    sB[col >> 2][c * 16 + p * 4 + (col & 3)] = (short)f2bf(v);
  }
  __syncthreads();
  int w = tid >> 6, l = tid & 63, lo = l & 15, ig = l >> 4;
  int nt = w & 1, mbase = (w >> 1) * 3;
  short8v bfrag[2];
  #pragma unroll
  for (int kc = 0; kc < 2; kc++)
    bfrag[kc] = *(const short8v*)&sB[nt * 16 + lo][kc * 32 + ig * 8];
  #pragma unroll
  for (int mi = 0; mi < 3; mi++) {
    int m = mbase + mi;
    float4v acc = (float4v){0.f, 0.f, 0.f, 0.f};
    #pragma unroll
    for (int kc = 0; kc < 2; kc++) {
      short8v a = *(const short8v*)(Wpe + (size_t)(m * 16 + lo) * 64 + kc * 32 + ig * 8);
      acc = __builtin_amdgcn_mfma_f32_16x16x32_bf16(a, bfrag[kc], acc, 0, 0, 0);
    }
    int wcoord = nt * 16 + lo;
    #pragma unroll
    for (int r = 0; r < 4; r++) {
      int d = m * 16 + ig * 4 + r;
      sF[wcoord][d] = acc[r] + pb[d];
    }
  }
  __syncthreads();
  if (tid < 32) {
    int wv = tid;
    float s = 0.f, ss = 0.f;
    for (int d = 0; d < 96; d++) { float v = sF[wv][d]; s += v; ss += v * v; }
    float m = s * (1.f / 96.f);
    float var = ss * (1.f / 96.f) - m * m;
    sM[wv] = m; sR[wv] = rsqrtf(var + 1e-5f);
  }
  __syncthreads();
  for (int id = tid; id < 3072; id += 256) {
    int d = id >> 5, wv = id & 31;
    float v = (sF[wv][d] - sM[wv]) * sR[wv] * pg[d] + pbeta[d];
    f1[(((b * 96 + d) * 12 + z) * 32 + h) * 32 + wv] = v;
  }
}

// ---------------- z-interp + encoder proj (MFMA) -> X token-major bf16 ----------------
__global__ __launch_bounds__(256) void k_ie(const float* __restrict__ f1, const float* __restrict__ ef,
    const short* __restrict__ Wenc, const float* __restrict__ eb, const int* __restrict__ T,
    unsigned* __restrict__ Xg) {
  int x = blockIdx.x;
  int b = x >> 9, chunk = x & 511;
  int v0 = chunk * 64;
  int z = v0 >> 10, rp = v0 & 1023;
  int zl = T[192 + z], zr = T[224 + z];
  float wt = ((const float*)T)[256 + z];
  __shared__ short sEb[64][104];
  int tid = threadIdx.x;
  for (int id = tid; id < 6144; id += 256) {
    int c = id >> 6, vs = id & 63;
    sEb[vs][c] = (short)f2bf(ef[(size_t)(b * 96 + c) * 32768 + v0 + vs]);
  }
  __syncthreads();
  int w = tid >> 6, l = tid & 63, lo = l & 15, ig = l >> 4;
  int vcol = w * 16 + lo;
  short8v bfrag[3];
  #pragma unroll
  for (int kc = 0; kc < 3; kc++)
    bfrag[kc] = *(const short8v*)&sEb[vcol][kc * 32 + ig * 8];
  float4v acc[6];
  #pragma unroll
  for (int m = 0; m < 6; m++) {
    acc[m] = (float4v){0.f, 0.f, 0.f, 0.f};
    #pragma unroll
    for (int kc = 0; kc < 3; kc++) {
      short8v a = *(const short8v*)(Wenc + (size_t)(m * 16 + lo) * 96 + kc * 32 + ig * 8);
      acc[m] = __builtin_amdgcn_mfma_f32_16x16x32_bf16(a, bfrag[kc], acc[m], 0, 0, 0);
    }
  }
  int zb = z >> 2, tz = z & 3;
  int h0 = (chunk & 15) * 2;
  int h = h0 + (vcol >> 5), wc = vcol & 31;
  int win = ((b * 8 + zb) * 8 + (h >> 2)) * 8 + (wc >> 2);
  int t = tz * 16 + (h & 3) * 4 + (wc & 3);
  size_t xbase = (size_t)(win * 64 + t) * 48;
  float wl = 1.f - wt;
  #pragma unroll
  for (int m = 0; m < 6; m++) {
    #pragma unroll
    for (int rr = 0; rr < 2; rr++) {
      int d0 = m * 16 + ig * 4 + rr * 2;
      const float* p1a = f1 + ((size_t)(b * 96 + d0) * 12 + zl) * 1024 + rp + vcol;
      const float* p2a = f1 + ((size_t)(b * 96 + d0) * 12 + zr) * 1024 + rp + vcol;
      const float* p1b = f1 + ((size_t)(b * 96 + d0 + 1) * 12 + zl) * 1024 + rp + vcol;
      const float* p2b = f1 + ((size_t)(b * 96 + d0 + 1) * 12 + zr) * 1024 + rp + vcol;
      float va = acc[m][rr * 2] + eb[d0] + wl * p1a[0] + wt * p2a[0];
      float vb = acc[m][rr * 2 + 1] + eb[d0 + 1] + wl * p1b[0] + wt * p2b[0];
      Xg[xbase + m * 8 + ig * 2 + rr] = pk2(va, vb);
    }
  }
}

// ---------------- fused LN + QKV + attention + proj ----------------
__global__ __launch_bounds__(256) void k_fatt(const unsigned* __restrict__ Xg,
    const short* __restrict__ Wq, const float* __restrict__ qb,
    const float* __restrict__ lg, const float* __restrict__ lb,
    const short* __restrict__ Wa, const float* __restrict__ ab,
    const float* __restrict__ Bt, short* __restrict__ Xt) {
  int win = blockIdx.x;
  __shared__ short sA[64][104];
  __shared__ short sQP[4][16][104];
  __shared__ short sK[6144];
  __shared__ short sVt[96][72];
  __shared__ float sMn[64], sRs[64];
  int tid = threadIdx.x;
  int w = tid >> 6, l = tid & 63, lo = l & 15, ig = l >> 4;
  const float scale = 0.17677669529663687f;

  for (int id = tid; id < 3072; id += 256) {
    int row = id / 48, c2 = id % 48;
    *(unsigned*)&sA[row][c2 * 2] = Xg[(size_t)(win * 64 + row) * 48 + c2];
  }
  __syncthreads();
  {
    int token = tid >> 2, jl = tid & 3;
    float s = 0.f, ss = 0.f;
    #pragma unroll
    for (int i = 0; i < 12; i++) {
      unsigned u = *(unsigned*)&sA[token][jl * 24 + i * 2];
      float v0 = bfl(u), v1 = bfh(u);
      s += v0 + v1; ss += v0 * v0 + v1 * v1;
    }
    s += __shfl_xor(s, 1); ss += __shfl_xor(ss, 1);
    s += __shfl_xor(s, 2); ss += __shfl_xor(ss, 2);
    if (jl == 0) {
      float m = s * (1.f / 96.f);
      sMn[token] = m;
      sRs[token] = rsqrtf(ss * (1.f / 96.f) - m * m + 1e-5f);
    }
  }
  __syncthreads();
  {
    int tok = w * 16 + lo;
    float m = sMn[tok], rr = sRs[tok];
    short8v a[3];
    #pragma unroll
    for (int kc = 0; kc < 3; kc++) {
      short8v raw = *(const short8v*)&sA[tok][kc * 32 + ig * 8];
      short8v t;
      #pragma unroll
      for (int jj = 0; jj < 8; jj++) {
        int c = kc * 32 + ig * 8 + jj;
        float v = (bfs(raw[jj]) - m) * rr * lg[c] + lb[c];
        t[jj] = (short)f2bf(v);
      }
      a[kc] = t;
    }
    for (int nt = 0; nt < 18; nt++) {
      float4v acc = (float4v){0.f, 0.f, 0.f, 0.f};
      #pragma unroll
      for (int kc = 0; kc < 3; kc++) {
        short8v bfr = *(const short8v*)(Wq + (size_t)(nt * 16 + lo) * 96 + kc * 32 + ig * 8);
        acc = __builtin_amdgcn_mfma_f32_16x16x32_bf16(a[kc], bfr, acc, 0, 0, 0);
      }
      int out = nt * 16 + lo;
      float bias = qb[out];
      if (nt < 6) {
        int head = out >> 5, c = out & 31;
        #pragma unroll
        for (int r = 0; r < 4; r++)
          sQP[w][ig * 4 + r][head * 32 + c] = (short)f2bf((acc[r] + bias) * scale);
      } else if (nt < 12) {
        int o2 = out - 96, head = o2 >> 5, c = o2 & 31;
        #pragma unroll
        for (int r = 0; r < 4; r++) {
          int row = head * 64 + w * 16 + ig * 4 + r;
          sK[row * 32 + (((c >> 3) ^ ((row >> 1) & 3)) << 3) + (c & 7)] =
              (short)f2bf(acc[r] + bias);
        }
      } else {
        int o2 = out - 192;
        #pragma unroll
        for (int r = 0; r < 4; r++)
          sVt[o2][w * 16 + ig * 4 + r] = (short)f2bf(acc[r] + bias);
      }
    }
  }
  __syncthreads();
  short8v qf[3];
  #pragma unroll
  for (int h = 0; h < 3; h++)
    qf[h] = *(const short8v*)&sQP[w][lo][h * 32 + ig * 8];
  float oreg[3][2][4];
  #pragma unroll
  for (int h = 0; h < 3; h++) {
    short8v kf[4];
    #pragma unroll
    for (int nt = 0; nt < 4; nt++) {
      int row = h * 64 + nt * 16 + lo;
      kf[nt] = *(const short8v*)&sK[row * 32 + ((ig ^ ((row >> 1) & 3)) << 3)];
    }
    float4v s[4];
    #pragma unroll
    for (int nt = 0; nt < 4; nt++)
      s[nt] = __builtin_amdgcn_mfma_f32_16x16x32_bf16(qf[h], kf[nt], (float4v){0.f, 0.f, 0.f, 0.f}, 0, 0, 0);
    const float* bt = Bt + h * 4096;
    #pragma unroll
    for (int r = 0; r < 4; r++) {
      int tok = w * 16 + ig * 4 + r;
      float v[4];
      float mx = -1e30f;
      #pragma unroll
      for (int nt = 0; nt < 4; nt++) {
        v[nt] = s[nt][r] + bt[tok * 64 + nt * 16 + lo];
        mx = fmaxf(mx, v[nt]);
      }
      mx = fmaxf(mx, __shfl_xor(mx, 1));
      mx = fmaxf(mx, __shfl_xor(mx, 2));
      mx = fmaxf(mx, __shfl_xor(mx, 4));
      mx = fmaxf(mx, __shfl_xor(mx, 8));
      float sm = 0.f;
      #pragma unroll
      for (int nt = 0; nt < 4; nt++) { v[nt] = __expf(v[nt] - mx); sm += v[nt]; }
      sm += __shfl_xor(sm, 1);
      sm += __shfl_xor(sm, 2);
      sm += __shfl_xor(sm, 4);
      sm += __shfl_xor(sm, 8);
      float inv = 1.f / sm;
      #pragma unroll
      for (int nt = 0; nt < 4; nt++)
        sQP[w][ig * 4 + r][nt * 16 + lo] = (short)f2bf(v[nt] * inv);
    }
    short8v pa[2];
    #pragma unroll
    for (int kc = 0; kc < 2; kc++)
      pa[kc] = *(const short8v*)&sQP[w][lo][kc * 32 + ig * 8];
    #pragma unroll
    for (int ct = 0; ct < 2; ct++) {
      short8v vb0 = *(const short8v*)&sVt[h * 32 + ct * 16 + lo][ig * 8];
      short8v vb1 = *(const short8v*)&sVt[h * 32 + ct * 16 + lo][32 + ig * 8];
      float4v o = __builtin_amdgcn_mfma_f32_16x16x32_bf16(pa[0], vb0, (float4v){0.f, 0.f, 0.f, 0.f}, 0, 0, 0);
      o = __builtin_amdgcn_mfma_f32_16x16x32_bf16(pa[1], vb1, o, 0, 0, 0);
      #pragma unroll
      for (int r = 0; r < 4; r++)
        oreg[h][ct][r] = o[r];
    }
  }
  __syncthreads();
  #pragma unroll
  for (int h = 0; h < 3; h++)
    #pragma unroll
    for (int ct = 0; ct < 2; ct++)
      #pragma unroll
      for (int r = 0; r < 4; r++) {
        int tok = w * 16 + ig * 4 + r;
        int ch = h * 32 + ct * 16 + lo;
        sK[o_idx(tok, ch)] = (short)f2bf(oreg[h][ct][r]);
      }
  {
    int tok2 = w * 16 + lo;
    short8v a[3];
    #pragma unroll
    for (int kc = 0; kc < 3; kc++) {
      int slot = kc * 4 + ig;
      int sw = slot < 8 ? (slot ^ (tok2 & 7)) : (8 + ((slot - 8) ^ (tok2 & 3)));
      a[kc] = *(const short8v*)&sK[tok2 * 96 + sw * 8];
    }
    #pragma unroll
    for (int nt = 0; nt < 6; nt++) {
      float4v acc = (float4v){0.f, 0.f, 0.f, 0.f};
      #pragma unroll
      for (int kc = 0; kc < 3; kc++) {
        short8v bfr = *(const short8v*)(Wa + (size_t)(nt * 16 + lo) * 96 + kc * 32 + ig * 8);
        acc = __builtin_amdgcn_mfma_f32_16x16x32_bf16(a[kc], bfr, acc, 0, 0, 0);
      }
      int out = nt * 16 + lo;
      float bias = ab[out];
      #pragma unroll
      for (int r = 0; r < 4; r++) {
        int tok = w * 16 + ig * 4 + r;
        float res = bfs(sA[tok][out]);
        sA[tok][out] = (short)f2bf(acc[r] + bias + res);
      }
    }
  }
  __syncthreads();
  int b = win >> 9, zb = (win >> 6) & 7, hb = (win >> 3) & 7, wb = win & 7;
  for (int id = tid; id < 3072; id += 256) {
    int cc = id >> 10, rem = id & 1023, t = rem >> 4, ilp = rem & 15;
    unsigned pk = *(unsigned*)&sA[t][cc * 32 + ilp * 2];
    int tz = t >> 4, th = (t >> 2) & 3, tw = t & 3;
    size_t vox = (size_t)(zb * 4 + tz) * 1024 + (hb * 4 + th) * 32 + wb * 4 + tw;
    ((unsigned*)Xt)[((size_t)(b * 3 + cc) * 32768 + vox) * 16 + ilp] = pk;
  }
}

// ---------------- MFMA conv 3x3x3: 2z x 4h x 32w x 96o, XOR-swizzled LDS, bf16 y (round-12 config) ----------------
__global__ __launch_bounds__(256) void k_convM(const short* __restrict__ Xt,
    const short* __restrict__ Wt, const float* __restrict__ cb, short* __restrict__ y16,
    float* __restrict__ stats) {
  int x = blockIdx.x;
  int b = x >> 7, zp = (x >> 3) & 15, hq = x & 7;
  int tid = threadIdx.x;
  int wvi = tid >> 6, l = tid & 63;
  int lo = l & 15, ig = l >> 4;
  int hp = wvi & 1, mh = wvi >> 1;
  __shared__ short Xl[816 * 32];
  __shared__ float sG[16];
  if (tid < 16) sG[tid] = 0.f;
  float4v acc[3][2][2][2];
  #pragma unroll
  for (int mi = 0; mi < 3; mi++)
    #pragma unroll
    for (int zo = 0; zo < 2; zo++)
      #pragma unroll
      for (int hr = 0; hr < 2; hr++)
        #pragma unroll
        for (int n = 0; n < 2; n++) acc[mi][zo][hr][n] = (float4v){0.f, 0.f, 0.f, 0.f};

  for (int c = 0; c < 3; c++) {
    __syncthreads();
    for (int r = 0; r < 13; r++) {
      int id = tid + 256 * r;
      if (id < 3264) {
        int seg = id & 3, q = id >> 2;
        int zz = q / 204, rem = q - zz * 204;
        int hh = rem / 34, ww = rem - hh * 34;
        int gz = zp * 2 + zz - 1, gh = hq * 4 + hh - 1, gw = ww - 1;
        int4 val = {0, 0, 0, 0};
        if (gz >= 0 && gz < 32 && gh >= 0 && gh < 32 && gw >= 0 && gw < 32)
          val = *(const int4*)(Xt + ((size_t)((b * 3 + c) * 32768 + (gz << 10) + (gh << 5) + gw) * 32 + seg * 8));
        int slot = seg ^ ((q >> 1) & 3);
        *(int4*)(&Xl[q * 32 + slot * 8]) = val;
      }
    }
    __syncthreads();
    for (int dh = 0; dh < 3; dh++) {
      for (int dwv = 0; dwv < 3; dwv++) {
        short8v bfr[4][2][2];
        #pragma unroll
        for (int zr = 0; zr < 4; zr++)
          #pragma unroll
          for (int hr = 0; hr < 2; hr++)
            #pragma unroll
            for (int n = 0; n < 2; n++) {
              int vox = (zr * 6 + hp * 2 + hr + dh) * 34 + n * 16 + lo + dwv;
              bfr[zr][hr][n] = *(const short8v*)&Xl[vox * 32 + ((ig ^ ((vox >> 1) & 3)) * 8)];
            }
        #pragma unroll
        for (int dz = 0; dz < 3; dz++) {
          int tap = dz * 9 + dh * 3 + dwv;
          #pragma unroll
          for (int mi = 0; mi < 3; mi++) {
            short8v wf = *(const short8v*)(Wt +
                ((size_t)(tap * 96 + (mh * 3 + mi) * 16 + lo)) * 96 + c * 32 + ig * 8);
            #pragma unroll
            for (int zo = 0; zo < 2; zo++)
              #pragma unroll
              for (int hr = 0; hr < 2; hr++)
                #pragma unroll
                for (int n = 0; n < 2; n++)
                  acc[mi][zo][hr][n] = __builtin_amdgcn_mfma_f32_16x16x32_bf16(wf, bfr[zo + dz][hr][n], acc[mi][zo][hr][n], 0, 0, 0);
          }
        }
      }
    }
  }
  #pragma unroll
  for (int mi = 0; mi < 3; mi++) {
    #pragma unroll
    for (int r = 0; r < 4; r++) {
      int o = (mh * 3 + mi) * 16 + ig * 4 + r;
      float cbo = cb[o];
      float s = 0.f, ss = 0.f;
      #pragma unroll
      for (int zo = 0; zo < 2; zo++)
        #pragma unroll
        for (int hr = 0; hr < 2; hr++)
          #pragma unroll
          for (int n = 0; n < 2; n++) {
            float v = acc[mi][zo][hr][n][r] + cbo;
            int z = zp * 2 + zo;
            int h = hq * 4 + hp * 2 + hr;
            int vcol = n * 16 + lo;
            y16[((size_t)(b * 96 + o) << 15) + (z << 10) + (h << 5) + vcol] = (short)f2bf(v);
            s += v; ss += v * v;
          }
      s += __shfl_xor(s, 1); ss += __shfl_xor(ss, 1);
      s += __shfl_xor(s, 2); ss += __shfl_xor(ss, 2);
      s += __shfl_xor(s, 4); ss += __shfl_xor(ss, 4);
      s += __shfl_xor(s, 8); ss += __shfl_xor(ss, 8);
      if (lo == 0) {
        int gl = o / 12;
        atomicAdd(&sG[gl * 2], s);
        atomicAdd(&sG[gl * 2 + 1], ss);
      }
    }
  }
  __syncthreads();
  if (tid < 16) atomicAdd(&stats[b * 16 + tid], sG[tid]);
}

// ---------------- GN apply + GELU (bf16 y in) -> bf16 conv layout ----------------
__global__ __launch_bounds__(256) void k_gn(const short* __restrict__ y16, const float* __restrict__ stats,
    const float* __restrict__ gg, const float* __restrict__ gb, short* __restrict__ xt) {
  int x = blockIdx.x;
  int b = x / 1536, r = x % 1536, c = r / 512, vt = r % 512;
  int v0 = vt * 64;
  __shared__ float sT[64][33];
  int tid = threadIdx.x;
  const float invN = 1.f / 393216.f;
  {
    int ol = tid >> 3, vq = tid & 7;
    int o = c * 32 + ol, g = b * 8 + o / 12;
    float m = stats[2 * g] * invN;
    float var = stats[2 * g + 1] * invN - m * m;
    float rs = rsqrtf(var + 1e-5f) * gg[o];
    float bb = gb[o];
    short8v yv = *(const short8v*)&y16[((size_t)(b * 96 + o) << 15) + v0 + vq * 8];
    #pragma unroll
    for (int j = 0; j < 8; j++) {
      float val = (bfs(yv[j]) - m) * rs + bb;
      sT[vq * 8 + j][ol] = 0.5f * val * (1.f + erff(val * 0.70710678118654752f));
    }
  }
  __syncthreads();
  for (int id = tid; id < 1024; id += 256) {
    int v = id >> 4, p = id & 15;
    ((unsigned*)xt)[((size_t)(b * 3 + c) * 32768 + v0 + v) * 16 + p] = pk2(sT[v][2 * p], sT[v][2 * p + 1]);
  }
}

// ---------------- reconstruct (MFMA) + baseline z-interp ----------------
__global__ __launch_bounds__(256) void k_final(const short* __restrict__ f5b, const float* __restrict__ sp,
    const short* __restrict__ Wrec, const float* __restrict__ rb, const int* __restrict__ T,
    float* __restrict__ out) {
  int x = blockIdx.x;
  int b = x >> 10, chunk = x & 1023;
  int z = chunk >> 5, h = chunk & 31;
  int v0 = chunk * 32;
  int tid = threadIdx.x;
  int w = tid >> 6, l = tid & 63, lo = l & 15, ig = l >> 4;
  short8v afrag[2][3];
  #pragma unroll
  for (int mt = 0; mt < 2; mt++)
    #pragma unroll
    for (int kc = 0; kc < 3; kc++)
      afrag[mt][kc] = *(const short8v*)(f5b +
          ((size_t)(b * 3 + kc) * 32768 + v0 + mt * 16 + lo) * 32 + ig * 8);
  float4v acc[2][2];
  #pragma unroll
  for (int nt2 = 0; nt2 < 2; nt2++) {
    int jt = w * 2 + nt2;
    #pragma unroll
    for (int mt = 0; mt < 2; mt++) acc[mt][nt2] = (float4v){0.f, 0.f, 0.f, 0.f};
    #pragma unroll
    for (int kc = 0; kc < 3; kc++) {
      short8v bfr = *(const short8v*)(Wrec + (size_t)(jt * 16 + lo) * 96 + kc * 32 + ig * 8);
      #pragma unroll
      for (int mt = 0; mt < 2; mt++)
        acc[mt][nt2] = __builtin_amdgcn_mfma_f32_16x16x32_bf16(afrag[mt][kc], bfr, acc[mt][nt2], 0, 0, 0);
    }
  }
  const float* w64 = (const float*)(T + 128);
  #pragma unroll
  for (int mt = 0; mt < 2; mt++)
    #pragma unroll
    for (int nt2 = 0; nt2 < 2; nt2++) {
      int jt = w * 2 + nt2;
      #pragma unroll
      for (int r = 0; r < 4; r++) {
        int wv = mt * 16 + ig * 4 + r;
        int j = jt * 16 + lo;
        int o = j >> 5, dd = (j >> 4) & 1, e = (j >> 2) & 3, ff = j & 3;
        int Z = 2 * z + dd, H = 4 * h + e, W = 4 * wv + ff;
        int zl = T[Z], zr = T[64 + Z];
        float bw = w64[Z];
        const float* spb = sp + (size_t)(b * 4 + o) * 196608;
        float bval = (1.f - bw) * spb[(size_t)zl * 16384 + H * 128 + W]
                   + bw * spb[(size_t)zr * 16384 + H * 128 + W];
        out[((size_t)(b * 4 + o) * 64 + Z) * 16384 + H * 128 + W] = bval + acc[mt][nt2][r] + rb[o];
      }
    }
}

extern "C" void kernel_launch(void* const* d_in, const int* in_sizes, int n_in,
                              void* d_out, int out_size, void* d_ws, size_t ws_size,
                              hipStream_t stream) {
  const float* sp    = (const float*)d_in[0];
  const float* ef    = (const float*)d_in[1];
  const float* pe_w  = (const float*)d_in[2];
  const float* pe_b  = (const float*)d_in[3];
  const float* pe_g  = (const float*)d_in[4];
  const float* pe_be = (const float*)d_in[5];
  const float* enc_w = (const float*)d_in[6];
  const float* enc_b = (const float*)d_in[7];
  const float* ln_g  = (const float*)d_in[8];
  const float* ln_b  = (const float*)d_in[9];
  const float* qkv_w = (const float*)d_in[10];
  const float* qkv_b = (const float*)d_in[11];
  const float* at_w  = (const float*)d_in[12];
  const float* at_b  = (const float*)d_in[13];
  const float* rpb   = (const float*)d_in[14];
  const float* w1    = (const float*)d_in[15];
  const float* b1    = (const float*)d_in[16];
  const float* g1g   = (const float*)d_in[17];
  const float* g1b   = (const float*)d_in[18];
  const float* w2    = (const float*)d_in[19];
  const float* b2    = (const float*)d_in[20];
  const float* g2g   = (const float*)d_in[21];
  const float* g2b   = (const float*)d_in[22];
  const float* recw  = (const float*)d_in[23];
  const float* recb  = (const float*)d_in[24];
  const int*   sidx  = (const int*)d_in[25];
  float* out = (float*)d_out;

  char* ws = (char*)d_ws;
  unsigned* Xg = (unsigned*)ws;
  float* f1    = (float*)(ws + 25165824);
  short* XtA   = (short*)(ws + 25165824);
  short* Y16   = (short*)(ws + 50331648);
  int*   T     = (int*)(ws + 100663296);
  float* stats = (float*)(ws + 100665344);
  short* Wrec  = (short*)(ws + 100666368);

  char* dob = (char*)d_out;
  short* Wenc = (short*)(dob + 25165824);
  short* Wpe  = (short*)(dob + 25184256);
  short* Wqkv = (short*)(dob + 65937408);
  short* Waw  = (short*)(dob + 65992704);
  float* Bt   = (float*)(dob + 66011136);
  short* Wt1  = (short*)(dob + 66060288);
  short* Wt2  = (short*)(dob + 66557952);

  k_prep<<<2245, 256, 0, stream>>>(sidx, T, w1, Wt1, w2, Wt2, qkv_w, Wqkv,
                                   at_w, Waw, enc_w, Wenc, pe_w, Wpe, recw, Wrec, rpb, Bt);

  k_pe<<<1536, 256, 0, stream>>>(sp, Wpe, pe_b, pe_g, pe_be, f1);
  k_ie<<<2048, 256, 0, stream>>>(f1, ef, Wenc, enc_b, T, Xg);
  k_fatt<<<2048, 256, 0, stream>>>(Xg, Wqkv, qkv_b, ln_g, ln_b, Waw, at_b, Bt, XtA);

  hipMemsetAsync(stats, 0, 64 * sizeof(float), stream);
  k_convM<<<512, 256, 0, stream>>>(XtA, Wt1, b1, Y16, stats);
  k_gn<<<6144, 256, 0, stream>>>(Y16, stats, g1g, g1b, XtA);

  hipMemsetAsync(stats, 0, 64 * sizeof(float), stream);
  k_convM<<<512, 256, 0, stream>>>(XtA, Wt2, b2, Y16, stats);
  k_gn<<<6144, 256, 0, stream>>>(Y16, stats, g2g, g2b, XtA);

  k_final<<<4096, 256, 0, stream>>>(XtA, sp, Wrec, recb, T, out);
}

// Round 17
// 299.790 us; speedup vs baseline: 1.4882x; 1.0342x over previous
//
#include <hip/hip_runtime.h>
#include <hip/hip_bf16.h>
#include <math.h>

typedef __attribute__((ext_vector_type(8))) short short8v;
typedef __attribute__((ext_vector_type(4))) float float4v;

__device__ inline unsigned short f2bf(float f) {
  __hip_bfloat16 h = __float2bfloat16(f);
  return *reinterpret_cast<unsigned short*>(&h);
}
__device__ inline unsigned pk2(float a, float b) {
  return (unsigned)f2bf(a) | ((unsigned)f2bf(b) << 16);
}
__device__ inline float bfl(unsigned u) { return __uint_as_float(u << 16); }
__device__ inline float bfh(unsigned u) { return __uint_as_float(u & 0xffff0000u); }
__device__ inline float bfs(short s) { return __uint_as_float(((unsigned)(unsigned short)s) << 16); }

// O-in-sK swizzled index: row tok (96 shorts), 16B slots XOR'd within row
__device__ inline int o_idx(int tok, int ch) {
  int slot = ch >> 3;
  int sw = slot < 8 ? (slot ^ (tok & 7)) : (8 + ((slot - 8) ^ (tok & 3)));
  return tok * 96 + sw * 8 + (ch & 7);
}

// ---------------- merged prologue ----------------
__global__ __launch_bounds__(256) void k_prep(
    const int* __restrict__ sidx, int* __restrict__ T,
    const float* __restrict__ w1, short* __restrict__ Wt1,
    const float* __restrict__ w2, short* __restrict__ Wt2,
    const float* __restrict__ qkvw, short* __restrict__ Wqkv,
    const float* __restrict__ atw, short* __restrict__ Waw,
    const float* __restrict__ encw, short* __restrict__ Wenc,
    const float* __restrict__ pew, short* __restrict__ Wpe,
    const float* __restrict__ recw, short* __restrict__ Wrec,
    const float* __restrict__ rpb, float* __restrict__ Bt) {
  int bx = blockIdx.x;
  int tid = threadIdx.x;
  if (bx < 1944) {
    const float* w = bx < 972 ? w1 : w2;
    short* Wt = bx < 972 ? Wt1 : Wt2;
    int id = (bx < 972 ? bx : bx - 972) * 256 + tid;
    if (id < 248832) {
      float v = w[id];
      int o = id / 2592; int rem = id % 2592; int i = rem / 27; int tap = rem % 27;
      Wt[(tap * 96 + o) * 96 + i] = (short)f2bf(v);
    }
  } else if (bx < 2052) {
    int id = (bx - 1944) * 256 + tid;
    if (id < 27648) Wqkv[id] = (short)f2bf(qkvw[id]);
  } else if (bx < 2088) {
    int id = (bx - 2052) * 256 + tid;
    if (id < 9216) Waw[id] = (short)f2bf(atw[id]);
  } else if (bx < 2124) {
    int id = (bx - 2088) * 256 + tid;
    if (id < 9216) Wenc[id] = (short)f2bf(encw[id]);
  } else if (bx < 2148) {
    int id = (bx - 2124) * 256 + tid;
    if (id < 6144) Wpe[id] = (short)f2bf(pew[id]);
  } else if (bx < 2196) {
    int id = (bx - 2148) * 256 + tid;
    if (id < 12288) {
      int i = id >> 7, j = id & 127;
      Wrec[j * 96 + i] = (short)f2bf(recw[id]);
    }
  } else if (bx < 2244) {
    int id = (bx - 2196) * 256 + tid;
    if (id < 12288) {
      int head = id >> 12, rem = id & 4095, n = rem >> 6, m = rem & 63;
      int dz = (n >> 4) - (m >> 4), dh = ((n >> 2) & 3) - ((m >> 2) & 3), dw = (n & 3) - (m & 3);
      Bt[id] = rpb[((dz + 3) * 49 + (dh + 3) * 7 + (dw + 3)) * 3 + head];
    }
  } else {
    __shared__ float pos[12];
    int t = tid;
    if (t < 12) pos[t] = (float)sidx[t];
    __syncthreads();
    if (t < 64) {
      float zq = (float)t;
      int r = 0;
      while (r < 12 && pos[r] < zq) r++;
      int lft = r - 1; if (lft < 0) lft = 0; if (lft > 11) lft = 11;
      int rc = r; if (rc > 11) rc = 11;
      float lp = pos[lft], rp = pos[rc], d = rp - lp;
      float w = d > 0.f ? (zq - lp) / d : 0.5f;
      T[t] = lft; T[64 + t] = rc; ((float*)T)[128 + t] = w;
    } else if (t < 128) {
      int zq = t - 64;
      float zqf = (float)zq;
      if (zq < 32) {
        int r = 0;
        while (r < 12 && pos[r] * 0.5f < zqf) r++;
        int lft = r - 1; if (lft < 0) lft = 0; if (lft > 11) lft = 11;
        int rc = r; if (rc > 11) rc = 11;
        float lp = pos[lft] * 0.5f, rp = pos[rc] * 0.5f, d = rp - lp;
        float w = d > 0.f ? (zqf - lp) / d : 0.5f;
        T[192 + zq] = lft; T[224 + zq] = rc; ((float*)T)[256 + zq] = w;
      }
    }
  }
}

// ---------------- patch embed (MFMA) + LayerNorm ----------------
__global__ __launch_bounds__(256) void k_pe(const float* __restrict__ sp, const short* __restrict__ Wpe,
    const float* __restrict__ pb, const float* __restrict__ pg, const float* __restrict__ pbeta,
    float* __restrict__ f1) {
  int x = blockIdx.x;
  int b = x / 384, z = (x / 32) % 12, h = x % 32;
  __shared__ short sB[32][72];
  __shared__ float sF[32][97];
  __shared__ float sM[32], sR[32];
  int tid = threadIdx.x;
  for (int id = tid; id < 2048; id += 256) {
    int c = id >> 9, p = (id >> 7) & 3, col = id & 127;
    float v = sp[(((b * 4 + c) * 12 + z) * 128 + h * 4 + p) * 128 + col];
    sB[col >> 2][c * 16 + p * 4 + (col & 3)] = (short)f2bf(v);
  }
  __syncthreads();
  int w = tid >> 6, l = tid & 63, lo = l & 15, ig = l >> 4;
  int nt = w & 1, mbase = (w >> 1) * 3;
  short8v bfrag[2];
  #pragma unroll
  for (int kc = 0; kc < 2; kc++)
    bfrag[kc] = *(const short8v*)&sB[nt * 16 + lo][kc * 32 + ig * 8];
  #pragma unroll
  for (int mi = 0; mi < 3; mi++) {
    int m = mbase + mi;
    float4v acc = (float4v){0.f, 0.f, 0.f, 0.f};
    #pragma unroll
    for (int kc = 0; kc < 2; kc++) {
      short8v a = *(const short8v*)(Wpe + (size_t)(m * 16 + lo) * 64 + kc * 32 + ig * 8);
      acc = __builtin_amdgcn_mfma_f32_16x16x32_bf16(a, bfrag[kc], acc, 0, 0, 0);
    }
    int wcoord = nt * 16 + lo;
    #pragma unroll
    for (int r = 0; r < 4; r++) {
      int d = m * 16 + ig * 4 + r;
      sF[wcoord][d] = acc[r] + pb[d];
    }
  }
  __syncthreads();
  if (tid < 32) {
    int wv = tid;
    float s = 0.f, ss = 0.f;
    for (int d = 0; d < 96; d++) { float v = sF[wv][d]; s += v; ss += v * v; }
    float m = s * (1.f / 96.f);
    float var = ss * (1.f / 96.f) - m * m;
    sM[wv] = m; sR[wv] = rsqrtf(var + 1e-5f);
  }
  __syncthreads();
  for (int id = tid; id < 3072; id += 256) {
    int d = id >> 5, wv = id & 31;
    float v = (sF[wv][d] - sM[wv]) * sR[wv] * pg[d] + pbeta[d];
    f1[(((b * 96 + d) * 12 + z) * 32 + h) * 32 + wv] = v;
  }
}

// ---------------- z-interp + encoder proj (MFMA) -> X token-major bf16 ----------------
__global__ __launch_bounds__(256) void k_ie(const float* __restrict__ f1, const float* __restrict__ ef,
    const short* __restrict__ Wenc, const float* __restrict__ eb, const int* __restrict__ T,
    unsigned* __restrict__ Xg) {
  int x = blockIdx.x;
  int b = x >> 9, chunk = x & 511;
  int v0 = chunk * 64;
  int z = v0 >> 10, rp = v0 & 1023;
  int zl = T[192 + z], zr = T[224 + z];
  float wt = ((const float*)T)[256 + z];
  __shared__ short sEb[64][104];
  int tid = threadIdx.x;
  for (int id = tid; id < 6144; id += 256) {
    int c = id >> 6, vs = id & 63;
    sEb[vs][c] = (short)f2bf(ef[(size_t)(b * 96 + c) * 32768 + v0 + vs]);
  }
  __syncthreads();
  int w = tid >> 6, l = tid & 63, lo = l & 15, ig = l >> 4;
  int vcol = w * 16 + lo;
  short8v bfrag[3];
  #pragma unroll
  for (int kc = 0; kc < 3; kc++)
    bfrag[kc] = *(const short8v*)&sEb[vcol][kc * 32 + ig * 8];
  float4v acc[6];
  #pragma unroll
  for (int m = 0; m < 6; m++) {
    acc[m] = (float4v){0.f, 0.f, 0.f, 0.f};
    #pragma unroll
    for (int kc = 0; kc < 3; kc++) {
      short8v a = *(const short8v*)(Wenc + (size_t)(m * 16 + lo) * 96 + kc * 32 + ig * 8);
      acc[m] = __builtin_amdgcn_mfma_f32_16x16x32_bf16(a, bfrag[kc], acc[m], 0, 0, 0);
    }
  }
  int zb = z >> 2, tz = z & 3;
  int h0 = (chunk & 15) * 2;
  int h = h0 + (vcol >> 5), wc = vcol & 31;
  int win = ((b * 8 + zb) * 8 + (h >> 2)) * 8 + (wc >> 2);
  int t = tz * 16 + (h & 3) * 4 + (wc & 3);
  size_t xbase = (size_t)(win * 64 + t) * 48;
  float wl = 1.f - wt;
  #pragma unroll
  for (int m = 0; m < 6; m++) {
    #pragma unroll
    for (int rr = 0; rr < 2; rr++) {
      int d0 = m * 16 + ig * 4 + rr * 2;
      const float* p1a = f1 + ((size_t)(b * 96 + d0) * 12 + zl) * 1024 + rp + vcol;
      const float* p2a = f1 + ((size_t)(b * 96 + d0) * 12 + zr) * 1024 + rp + vcol;
      const float* p1b = f1 + ((size_t)(b * 96 + d0 + 1) * 12 + zl) * 1024 + rp + vcol;
      const float* p2b = f1 + ((size_t)(b * 96 + d0 + 1) * 12 + zr) * 1024 + rp + vcol;
      float va = acc[m][rr * 2] + eb[d0] + wl * p1a[0] + wt * p2a[0];
      float vb = acc[m][rr * 2 + 1] + eb[d0 + 1] + wl * p1b[0] + wt * p2b[0];
      Xg[xbase + m * 8 + ig * 2 + rr] = pk2(va, vb);
    }
  }
}

// ---------------- fused LN + QKV + attention + proj ----------------
__global__ __launch_bounds__(256) void k_fatt(const unsigned* __restrict__ Xg,
    const short* __restrict__ Wq, const float* __restrict__ qb,
    const float* __restrict__ lg, const float* __restrict__ lb,
    const short* __restrict__ Wa, const float* __restrict__ ab,
    const float* __restrict__ Bt, short* __restrict__ Xt) {
  int win = blockIdx.x;
  __shared__ short sA[64][104];
  __shared__ short sQP[4][16][104];
  __shared__ short sK[6144];
  __shared__ short sVt[96][72];
  __shared__ float sMn[64], sRs[64];
  int tid = threadIdx.x;
  int w = tid >> 6, l = tid & 63, lo = l & 15, ig = l >> 4;
  const float scale = 0.17677669529663687f;

  for (int id = tid; id < 3072; id += 256) {
    int row = id / 48, c2 = id % 48;
    *(unsigned*)&sA[row][c2 * 2] = Xg[(size_t)(win * 64 + row) * 48 + c2];
  }
  __syncthreads();
  {
    int token = tid >> 2, jl = tid & 3;
    float s = 0.f, ss = 0.f;
    #pragma unroll
    for (int i = 0; i < 12; i++) {
      unsigned u = *(unsigned*)&sA[token][jl * 24 + i * 2];
      float v0 = bfl(u), v1 = bfh(u);
      s += v0 + v1; ss += v0 * v0 + v1 * v1;
    }
    s += __shfl_xor(s, 1); ss += __shfl_xor(ss, 1);
    s += __shfl_xor(s, 2); ss += __shfl_xor(ss, 2);
    if (jl == 0) {
      float m = s * (1.f / 96.f);
      sMn[token] = m;
      sRs[token] = rsqrtf(ss * (1.f / 96.f) - m * m + 1e-5f);
    }
  }
  __syncthreads();
  {
    int tok = w * 16 + lo;
    float m = sMn[tok], rr = sRs[tok];
    short8v a[3];
    #pragma unroll
    for (int kc = 0; kc < 3; kc++) {
      short8v raw = *(const short8v*)&sA[tok][kc * 32 + ig * 8];
      short8v t;
      #pragma unroll
      for (int jj = 0; jj < 8; jj++) {
        int c = kc * 32 + ig * 8 + jj;
        float v = (bfs(raw[jj]) - m) * rr * lg[c] + lb[c];
        t[jj] = (short)f2bf(v);
      }
      a[kc] = t;
    }
    for (int nt = 0; nt < 18; nt++) {
      float4v acc = (float4v){0.f, 0.f, 0.f, 0.f};
      #pragma unroll
      for (int kc = 0; kc < 3; kc++) {
        short8v bfr = *(const short8v*)(Wq + (size_t)(nt * 16 + lo) * 96 + kc * 32 + ig * 8);
        acc = __builtin_amdgcn_mfma_f32_16x16x32_bf16(a[kc], bfr, acc, 0, 0, 0);
      }
      int out = nt * 16 + lo;
      float bias = qb[out];
      if (nt < 6) {
        int head = out >> 5, c = out & 31;
        #pragma unroll
        for (int r = 0; r < 4; r++)
          sQP[w][ig * 4 + r][head * 32 + c] = (short)f2bf((acc[r] + bias) * scale);
      } else if (nt < 12) {
        int o2 = out - 96, head = o2 >> 5, c = o2 & 31;
        #pragma unroll
        for (int r = 0; r < 4; r++) {
          int row = head * 64 + w * 16 + ig * 4 + r;
          sK[row * 32 + (((c >> 3) ^ ((row >> 1) & 3)) << 3) + (c & 7)] =
              (short)f2bf(acc[r] + bias);
        }
      } else {
        int o2 = out - 192;
        #pragma unroll
        for (int r = 0; r < 4; r++)
          sVt[o2][w * 16 + ig * 4 + r] = (short)f2bf(acc[r] + bias);
      }
    }
  }
  __syncthreads();
  short8v qf[3];
  #pragma unroll
  for (int h = 0; h < 3; h++)
    qf[h] = *(const short8v*)&sQP[w][lo][h * 32 + ig * 8];
  float oreg[3][2][4];
  #pragma unroll
  for (int h = 0; h < 3; h++) {
    short8v kf[4];
    #pragma unroll
    for (int nt = 0; nt < 4; nt++) {
      int row = h * 64 + nt * 16 + lo;
      kf[nt] = *(const short8v*)&sK[row * 32 + ((ig ^ ((row >> 1) & 3)) << 3)];
    }
    float4v s[4];
    #pragma unroll
    for (int nt = 0; nt < 4; nt++)
      s[nt] = __builtin_amdgcn_mfma_f32_16x16x32_bf16(qf[h], kf[nt], (float4v){0.f, 0.f, 0.f, 0.f}, 0, 0, 0);
    const float* bt = Bt + h * 4096;
    #pragma unroll
    for (int r = 0; r < 4; r++) {
      int tok = w * 16 + ig * 4 + r;
      float v[4];
      float mx = -1e30f;
      #pragma unroll
      for (int nt = 0; nt < 4; nt++) {
        v[nt] = s[nt][r] + bt[tok * 64 + nt * 16 + lo];
        mx = fmaxf(mx, v[nt]);
      }
      mx = fmaxf(mx, __shfl_xor(mx, 1));
      mx = fmaxf(mx, __shfl_xor(mx, 2));
      mx = fmaxf(mx, __shfl_xor(mx, 4));
      mx = fmaxf(mx, __shfl_xor(mx, 8));
      float sm = 0.f;
      #pragma unroll
      for (int nt = 0; nt < 4; nt++) { v[nt] = __expf(v[nt] - mx); sm += v[nt]; }
      sm += __shfl_xor(sm, 1);
      sm += __shfl_xor(sm, 2);
      sm += __shfl_xor(sm, 4);
      sm += __shfl_xor(sm, 8);
      float inv = 1.f / sm;
      #pragma unroll
      for (int nt = 0; nt < 4; nt++)
        sQP[w][ig * 4 + r][nt * 16 + lo] = (short)f2bf(v[nt] * inv);
    }
    short8v pa[2];
    #pragma unroll
    for (int kc = 0; kc < 2; kc++)
      pa[kc] = *(const short8v*)&sQP[w][lo][kc * 32 + ig * 8];
    #pragma unroll
    for (int ct = 0; ct < 2; ct++) {
      short8v vb0 = *(const short8v*)&sVt[h * 32 + ct * 16 + lo][ig * 8];
      short8v vb1 = *(const short8v*)&sVt[h * 32 + ct * 16 + lo][32 + ig * 8];
      float4v o = __builtin_amdgcn_mfma_f32_16x16x32_bf16(pa[0], vb0, (float4v){0.f, 0.f, 0.f, 0.f}, 0, 0, 0);
      o = __builtin_amdgcn_mfma_f32_16x16x32_bf16(pa[1], vb1, o, 0, 0, 0);
      #pragma unroll
      for (int r = 0; r < 4; r++)
        oreg[h][ct][r] = o[r];
    }
  }
  __syncthreads();
  #pragma unroll
  for (int h = 0; h < 3; h++)
    #pragma unroll
    for (int ct = 0; ct < 2; ct++)
      #pragma unroll
      for (int r = 0; r < 4; r++) {
        int tok = w * 16 + ig * 4 + r;
        int ch = h * 32 + ct * 16 + lo;
        sK[o_idx(tok, ch)] = (short)f2bf(oreg[h][ct][r]);
      }
  {
    int tok2 = w * 16 + lo;
    short8v a[3];
    #pragma unroll
    for (int kc = 0; kc < 3; kc++) {
      int slot = kc * 4 + ig;
      int sw = slot < 8 ? (slot ^ (tok2 & 7)) : (8 + ((slot - 8) ^ (tok2 & 3)));
      a[kc] = *(const short8v*)&sK[tok2 * 96 + sw * 8];
    }
    #pragma unroll
    for (int nt = 0; nt < 6; nt++) {
      float4v acc = (float4v){0.f, 0.f, 0.f, 0.f};
      #pragma unroll
      for (int kc = 0; kc < 3; kc++) {
        short8v bfr = *(const short8v*)(Wa + (size_t)(nt * 16 + lo) * 96 + kc * 32 + ig * 8);
        acc = __builtin_amdgcn_mfma_f32_16x16x32_bf16(a[kc], bfr, acc, 0, 0, 0);
      }
      int out = nt * 16 + lo;
      float bias = ab[out];
      #pragma unroll
      for (int r = 0; r < 4; r++) {
        int tok = w * 16 + ig * 4 + r;
        float res = bfs(sA[tok][out]);
        sA[tok][out] = (short)f2bf(acc[r] + bias + res);
      }
    }
  }
  __syncthreads();
  int b = win >> 9, zb = (win >> 6) & 7, hb = (win >> 3) & 7, wb = win & 7;
  for (int id = tid; id < 3072; id += 256) {
    int cc = id >> 10, rem = id & 1023, t = rem >> 4, ilp = rem & 15;
    unsigned pk = *(unsigned*)&sA[t][cc * 32 + ilp * 2];
    int tz = t >> 4, th = (t >> 2) & 3, tw = t & 3;
    size_t vox = (size_t)(zb * 4 + tz) * 1024 + (hb * 4 + th) * 32 + wb * 4 + tw;
    ((unsigned*)Xt)[((size_t)(b * 3 + cc) * 32768 + vox) * 16 + ilp] = pk;
  }
}

// ---------------- MFMA conv 3x3x3: global_load_lds staging (linear dest, pre-swizzled source) ----------------
__global__ __launch_bounds__(256) void k_convM(const short* __restrict__ Xt,
    const short* __restrict__ Wt, const float* __restrict__ cb, short* __restrict__ y16,
    float* __restrict__ stats, const short* __restrict__ zerobuf) {
  int x = blockIdx.x;
  int b = x >> 7, zp = (x >> 3) & 15, hq = x & 7;
  int tid = threadIdx.x;
  int wvi = tid >> 6, l = tid & 63;
  int lo = l & 15, ig = l >> 4;
  int hp = wvi & 1, mh = wvi >> 1;
  __shared__ short Xl[816 * 32];
  __shared__ float sG[16];
  if (tid < 16) sG[tid] = 0.f;
  float4v acc[3][2][2][2];
  #pragma unroll
  for (int mi = 0; mi < 3; mi++)
    #pragma unroll
    for (int zo = 0; zo < 2; zo++)
      #pragma unroll
      for (int hr = 0; hr < 2; hr++)
        #pragma unroll
        for (int n = 0; n < 2; n++) acc[mi][zo][hr][n] = (float4v){0.f, 0.f, 0.f, 0.f};

  for (int c = 0; c < 3; c++) {
    __syncthreads();
    const short* cXt = Xt + (size_t)(b * 3 + c) * 1048576;
    // direct-to-LDS staging: linear LDS dest (id*16 bytes), source pre-swizzled
    for (int r = 0; r < 13; r++) {
      int id = tid + 256 * r;
      if (id < 3264) {
        int lslot = id & 3, q = id >> 2;
        int seg = lslot ^ ((q >> 1) & 3);
        int zz = q / 204, rem = q - zz * 204;
        int hh = rem / 34, ww = rem - hh * 34;
        int gz = zp * 2 + zz - 1, gh = hq * 4 + hh - 1, gw = ww - 1;
        bool ok = gz >= 0 && gz < 32 && gh >= 0 && gh < 32 && gw >= 0 && gw < 32;
        const void* src = ok ? (const void*)(cXt + (((gz << 10) + (gh << 5) + gw) * 32 + seg * 8))
                             : (const void*)zerobuf;
        void* dst = (void*)&Xl[(r * 256 + (tid & ~63)) * 8];   // wave-uniform base; HW adds lane*16B
        __builtin_amdgcn_global_load_lds(src, dst, 16, 0, 0);
      }
    }
    __syncthreads();
    for (int dh = 0; dh < 3; dh++) {
      for (int dwv = 0; dwv < 3; dwv++) {
        short8v bfr[4][2][2];
        #pragma unroll
        for (int zr = 0; zr < 4; zr++)
          #pragma unroll
          for (int hr = 0; hr < 2; hr++)
            #pragma unroll
            for (int n = 0; n < 2; n++) {
              int vox = (zr * 6 + hp * 2 + hr + dh) * 34 + n * 16 + lo + dwv;
              bfr[zr][hr][n] = *(const short8v*)&Xl[vox * 32 + ((ig ^ ((vox >> 1) & 3)) * 8)];
            }
        #pragma unroll
        for (int dz = 0; dz < 3; dz++) {
          int tap = dz * 9 + dh * 3 + dwv;
          #pragma unroll
          for (int mi = 0; mi < 3; mi++) {
            short8v wf = *(const short8v*)(Wt +
                ((size_t)(tap * 96 + (mh * 3 + mi) * 16 + lo)) * 96 + c * 32 + ig * 8);
            #pragma unroll
            for (int zo = 0; zo < 2; zo++)
              #pragma unroll
              for (int hr = 0; hr < 2; hr++)
                #pragma unroll
                for (int n = 0; n < 2; n++)
                  acc[mi][zo][hr][n] = __builtin_amdgcn_mfma_f32_16x16x32_bf16(wf, bfr[zo + dz][hr][n], acc[mi][zo][hr][n], 0, 0, 0);
          }
        }
      }
    }
  }
  #pragma unroll
  for (int mi = 0; mi < 3; mi++) {
    #pragma unroll
    for (int r = 0; r < 4; r++) {
      int o = (mh * 3 + mi) * 16 + ig * 4 + r;
      float cbo = cb[o];
      float s = 0.f, ss = 0.f;
      #pragma unroll
      for (int zo = 0; zo < 2; zo++)
        #pragma unroll
        for (int hr = 0; hr < 2; hr++)
          #pragma unroll
          for (int n = 0; n < 2; n++) {
            float v = acc[mi][zo][hr][n][r] + cbo;
            int z = zp * 2 + zo;
            int h = hq * 4 + hp * 2 + hr;
            int vcol = n * 16 + lo;
            y16[((size_t)(b * 96 + o) << 15) + (z << 10) + (h << 5) + vcol] = (short)f2bf(v);
            s += v; ss += v * v;
          }
      s += __shfl_xor(s, 1); ss += __shfl_xor(ss, 1);
      s += __shfl_xor(s, 2); ss += __shfl_xor(ss, 2);
      s += __shfl_xor(s, 4); ss += __shfl_xor(ss, 4);
      s += __shfl_xor(s, 8); ss += __shfl_xor(ss, 8);
      if (lo == 0) {
        int gl = o / 12;
        atomicAdd(&sG[gl * 2], s);
        atomicAdd(&sG[gl * 2 + 1], ss);
      }
    }
  }
  __syncthreads();
  if (tid < 16) atomicAdd(&stats[b * 16 + tid], sG[tid]);
}

// ---------------- GN apply + GELU (bf16 y in) -> bf16 conv layout ----------------
__global__ __launch_bounds__(256) void k_gn(const short* __restrict__ y16, const float* __restrict__ stats,
    const float* __restrict__ gg, const float* __restrict__ gb, short* __restrict__ xt) {
  int x = blockIdx.x;
  int b = x / 1536, r = x % 1536, c = r / 512, vt = r % 512;
  int v0 = vt * 64;
  __shared__ float sT[64][33];
  int tid = threadIdx.x;
  const float invN = 1.f / 393216.f;
  {
    int ol = tid >> 3, vq = tid & 7;
    int o = c * 32 + ol, g = b * 8 + o / 12;
    float m = stats[2 * g] * invN;
    float var = stats[2 * g + 1] * invN - m * m;
    float rs = rsqrtf(var + 1e-5f) * gg[o];
    float bb = gb[o];
    short8v yv = *(const short8v*)&y16[((size_t)(b * 96 + o) << 15) + v0 + vq * 8];
    #pragma unroll
    for (int j = 0; j < 8; j++) {
      float val = (bfs(yv[j]) - m) * rs + bb;
      sT[vq * 8 + j][ol] = 0.5f * val * (1.f + erff(val * 0.70710678118654752f));
    }
  }
  __syncthreads();
  for (int id = tid; id < 1024; id += 256) {
    int v = id >> 4, p = id & 15;
    ((unsigned*)xt)[((size_t)(b * 3 + c) * 32768 + v0 + v) * 16 + p] = pk2(sT[v][2 * p], sT[v][2 * p + 1]);
  }
}

// ---------------- reconstruct (MFMA) + baseline z-interp ----------------
__global__ __launch_bounds__(256) void k_final(const short* __restrict__ f5b, const float* __restrict__ sp,
    const short* __restrict__ Wrec, const float* __restrict__ rb, const int* __restrict__ T,
    float* __restrict__ out) {
  int x = blockIdx.x;
  int b = x >> 10, chunk = x & 1023;
  int z = chunk >> 5, h = chunk & 31;
  int v0 = chunk * 32;
  int tid = threadIdx.x;
  int w = tid >> 6, l = tid & 63, lo = l & 15, ig = l >> 4;
  short8v afrag[2][3];
  #pragma unroll
  for (int mt = 0; mt < 2; mt++)
    #pragma unroll
    for (int kc = 0; kc < 3; kc++)
      afrag[mt][kc] = *(const short8v*)(f5b +
          ((size_t)(b * 3 + kc) * 32768 + v0 + mt * 16 + lo) * 32 + ig * 8);
  float4v acc[2][2];
  #pragma unroll
  for (int nt2 = 0; nt2 < 2; nt2++) {
    int jt = w * 2 + nt2;
    #pragma unroll
    for (int mt = 0; mt < 2; mt++) acc[mt][nt2] = (float4v){0.f, 0.f, 0.f, 0.f};
    #pragma unroll
    for (int kc = 0; kc < 3; kc++) {
      short8v bfr = *(const short8v*)(Wrec + (size_t)(jt * 16 + lo) * 96 + kc * 32 + ig * 8);
      #pragma unroll
      for (int mt = 0; mt < 2; mt++)
        acc[mt][nt2] = __builtin_amdgcn_mfma_f32_16x16x32_bf16(afrag[mt][kc], bfr, acc[mt][nt2], 0, 0, 0);
    }
  }
  const float* w64 = (const float*)(T + 128);
  #pragma unroll
  for (int mt = 0; mt < 2; mt++)
    #pragma unroll
    for (int nt2 = 0; nt2 < 2; nt2++) {
      int jt = w * 2 + nt2;
      #pragma unroll
      for (int r = 0; r < 4; r++) {
        int wv = mt * 16 + ig * 4 + r;
        int j = jt * 16 + lo;
        int o = j >> 5, dd = (j >> 4) & 1, e = (j >> 2) & 3, ff = j & 3;
        int Z = 2 * z + dd, H = 4 * h + e, W = 4 * wv + ff;
        int zl = T[Z], zr = T[64 + Z];
        float bw = w64[Z];
        const float* spb = sp + (size_t)(b * 4 + o) * 196608;
        float bval = (1.f - bw) * spb[(size_t)zl * 16384 + H * 128 + W]
                   + bw * spb[(size_t)zr * 16384 + H * 128 + W];
        out[((size_t)(b * 4 + o) * 64 + Z) * 16384 + H * 128 + W] = bval + acc[mt][nt2][r] + rb[o];
      }
    }
}

extern "C" void kernel_launch(void* const* d_in, const int* in_sizes, int n_in,
                              void* d_out, int out_size, void* d_ws, size_t ws_size,
                              hipStream_t stream) {
  const float* sp    = (const float*)d_in[0];
  const float* ef    = (const float*)d_in[1];
  const float* pe_w  = (const float*)d_in[2];
  const float* pe_b  = (const float*)d_in[3];
  const float* pe_g  = (const float*)d_in[4];
  const float* pe_be = (const float*)d_in[5];
  const float* enc_w = (const float*)d_in[6];
  const float* enc_b = (const float*)d_in[7];
  const float* ln_g  = (const float*)d_in[8];
  const float* ln_b  = (const float*)d_in[9];
  const float* qkv_w = (const float*)d_in[10];
  const float* qkv_b = (const float*)d_in[11];
  const float* at_w  = (const float*)d_in[12];
  const float* at_b  = (const float*)d_in[13];
  const float* rpb   = (const float*)d_in[14];
  const float* w1    = (const float*)d_in[15];
  const float* b1    = (const float*)d_in[16];
  const float* g1g   = (const float*)d_in[17];
  const float* g1b   = (const float*)d_in[18];
  const float* w2    = (const float*)d_in[19];
  const float* b2    = (const float*)d_in[20];
  const float* g2g   = (const float*)d_in[21];
  const float* g2b   = (const float*)d_in[22];
  const float* recw  = (const float*)d_in[23];
  const float* recb  = (const float*)d_in[24];
  const int*   sidx  = (const int*)d_in[25];
  float* out = (float*)d_out;

  char* ws = (char*)d_ws;
  unsigned* Xg = (unsigned*)ws;
  float* f1    = (float*)(ws + 25165824);
  short* XtA   = (short*)(ws + 25165824);
  short* Y16   = (short*)(ws + 50331648);
  int*   T     = (int*)(ws + 100663296);
  float* stats = (float*)(ws + 100665344);
  short* zerob = (short*)(ws + 100665344 + 256);   // 64B zero stub (zeroed with stats)
  short* Wrec  = (short*)(ws + 100666368);

  char* dob = (char*)d_out;
  short* Wenc = (short*)(dob + 25165824);
  short* Wpe  = (short*)(dob + 25184256);
  short* Wqkv = (short*)(dob + 65937408);
  short* Waw  = (short*)(dob + 65992704);
  float* Bt   = (float*)(dob + 66011136);
  short* Wt1  = (short*)(dob + 66060288);
  short* Wt2  = (short*)(dob + 66557952);

  k_prep<<<2245, 256, 0, stream>>>(sidx, T, w1, Wt1, w2, Wt2, qkv_w, Wqkv,
                                   at_w, Waw, enc_w, Wenc, pe_w, Wpe, recw, Wrec, rpb, Bt);

  k_pe<<<1536, 256, 0, stream>>>(sp, Wpe, pe_b, pe_g, pe_be, f1);
  k_ie<<<2048, 256, 0, stream>>>(f1, ef, Wenc, enc_b, T, Xg);
  k_fatt<<<2048, 256, 0, stream>>>(Xg, Wqkv, qkv_b, ln_g, ln_b, Waw, at_b, Bt, XtA);

  hipMemsetAsync(stats, 0, 384, stream);   // stats (256B) + zero stub (64B+)
  k_convM<<<512, 256, 0, stream>>>(XtA, Wt1, b1, Y16, stats, zerob);
  k_gn<<<6144, 256, 0, stream>>>(Y16, stats, g1g, g1b, XtA);

  hipMemsetAsync(stats, 0, 384, stream);
  k_convM<<<512, 256, 0, stream>>>(XtA, Wt2, b2, Y16, stats, zerob);
  k_gn<<<6144, 256, 0, stream>>>(Y16, stats, g2g, g2b, XtA);

  k_final<<<4096, 256, 0, stream>>>(XtA, sp, Wrec, recb, T, out);
}